// Round 1
// baseline (1802.087 us; speedup 1.0000x reference)
//
#include <hip/hip_runtime.h>
#include <hip/hip_bf16.h>

// SAGEConv(mean) + L2norm + ReLU + BatchNorm(train stats) + FC
// N=100000 nodes, E=1200000 edges, F=H=64, C=16. All f32.
//
// ws layout (floats): [sums: N*64][cnt: N][stats: 128]
// sums is reused in-place as the post-ReLU h buffer by k_fused.

#define WF 64

__device__ __forceinline__ int swz(int row, int col) {
    // 128x64 LDS tile, bank-swizzled: rotate columns by 4*row (keeps quads contiguous)
    return (row << 6) + ((col + ((row << 2) & 63)) & 63);
}

// ---------------------------------------------------------------- scatter-mean
__global__ __launch_bounds__(256) void k_scatter(
        const int* __restrict__ eidx, const float4* __restrict__ x4,
        float* __restrict__ sums, float* __restrict__ cnt, int E) {
    int t = blockIdx.x * 256 + threadIdx.x;
    int e = t >> 4;
    int c = t & 15;
    if (e >= E) return;
    int src = eidx[e];
    int dst = eidx[E + e];
    float4 v = x4[(size_t)src * 16 + c];
    float* d = sums + (size_t)dst * 64 + c * 4;
    unsafeAtomicAdd(d + 0, v.x);
    unsafeAtomicAdd(d + 1, v.y);
    unsafeAtomicAdd(d + 2, v.z);
    unsafeAtomicAdd(d + 3, v.w);
    if (c == 0) unsafeAtomicAdd(cnt + dst, 1.0f);
}

// ------------------------------- fused: [mean|x] @ [Wl;Wr]^T + bl, L2norm, ReLU,
// ------------------------------- BN partial stats; writes r back in-place to hbuf
__global__ __launch_bounds__(256) void k_fused(
        const float* __restrict__ x,
        const float* __restrict__ Wl, const float* __restrict__ bl,
        const float* __restrict__ Wr,
        float* __restrict__ hbuf /* in: sums, out: relu'd normalized h */,
        const float* __restrict__ cnt,
        float* __restrict__ stats, int N) {
    __shared__ float sW[128 * 64];   // sW[k][j] = (k<64 ? Wl[j][k] : Wr[j][k-64]), swizzled
    __shared__ float sA[128 * 64];   // sA[k][n] = (k<64 ? mean[n][k] : x[n][k-64]), swizzled

    const int tid = threadIdx.x;
    const int n0 = blockIdx.x * 64;

    // ---- stage weights (coalesced global reads; swizzled LDS writes)
    for (int i = tid; i < 64 * 64; i += 256) {
        int j = i >> 6, k = i & 63;
        float wl = Wl[i];
        float wr = Wr[i];
        sW[swz(k, j)] = wl;
        sW[swz(k + 64, j)] = wr;
    }

    // ---- stage A: 64 nodes x 128 K (mean in rows 0..63, x in rows 64..127)
    {
        const int f0 = (tid & 15) * 4;
        for (int s = 0; s < 4; ++s) {
            int nl = (tid >> 4) + s * 16;     // 0..63
            int n = n0 + nl;
            float4 vs = make_float4(0.f, 0.f, 0.f, 0.f);
            float4 vx = vs;
            float inv = 0.f;
            if (n < N) {
                inv = 1.0f / fmaxf(cnt[n], 1.0f);
                vs = *(const float4*)(hbuf + (size_t)n * 64 + f0);
                vx = *(const float4*)(x + (size_t)n * 64 + f0);
            }
            float mv[4] = {vs.x * inv, vs.y * inv, vs.z * inv, vs.w * inv};
            float xv[4] = {vx.x, vx.y, vx.z, vx.w};
#pragma unroll
            for (int p = 0; p < 4; ++p) {
                sA[swz(f0 + p, nl)] = mv[p];
                sA[swz(f0 + p + 64, nl)] = xv[p];
            }
        }
    }
    __syncthreads();

    // ---- register-tiled GEMM: thread = (4 nodes) x (4 features)
    const int jbase = (tid & 15) * 4;
    const int nb = ((tid >> 4) & 3) * 4 + (tid >> 6) * 16;   // node base within block
    float acc[4][4] = {};
#pragma unroll 4
    for (int k = 0; k < 128; ++k) {
        const int rot = (k << 2) & 63;
        float4 a = *(const float4*)(sA + (k << 6) + ((nb + rot) & 63));
        float4 w = *(const float4*)(sW + (k << 6) + ((jbase + rot) & 63));
        acc[0][0] += a.x * w.x; acc[0][1] += a.x * w.y; acc[0][2] += a.x * w.z; acc[0][3] += a.x * w.w;
        acc[1][0] += a.y * w.x; acc[1][1] += a.y * w.y; acc[1][2] += a.y * w.z; acc[1][3] += a.y * w.w;
        acc[2][0] += a.z * w.x; acc[2][1] += a.z * w.y; acc[2][2] += a.z * w.z; acc[2][3] += a.z * w.w;
        acc[3][0] += a.w * w.x; acc[3][1] += a.w * w.y; acc[3][2] += a.w * w.z; acc[3][3] += a.w * w.w;
    }

    // ---- epilogue: +bias, row L2 norm (16-lane group = one node row), ReLU, store
    float4 blv = *(const float4*)(bl + jbase);
    float psum[4] = {0.f, 0.f, 0.f, 0.f};
    float psq[4] = {0.f, 0.f, 0.f, 0.f};
#pragma unroll
    for (int q = 0; q < 4; ++q) {
        float h0 = acc[q][0] + blv.x;
        float h1 = acc[q][1] + blv.y;
        float h2 = acc[q][2] + blv.z;
        float h3 = acc[q][3] + blv.w;
        float ss = h0 * h0 + h1 * h1 + h2 * h2 + h3 * h3;
        ss += __shfl_xor(ss, 1);
        ss += __shfl_xor(ss, 2);
        ss += __shfl_xor(ss, 4);
        ss += __shfl_xor(ss, 8);
        float sc = 1.0f / fmaxf(sqrtf(ss), 1e-12f);
        float r0 = fmaxf(h0 * sc, 0.f);
        float r1 = fmaxf(h1 * sc, 0.f);
        float r2 = fmaxf(h2 * sc, 0.f);
        float r3 = fmaxf(h3 * sc, 0.f);
        int n = n0 + nb + q;
        if (n < N) {
            *(float4*)(hbuf + (size_t)n * 64 + jbase) = make_float4(r0, r1, r2, r3);
            psum[0] += r0; psum[1] += r1; psum[2] += r2; psum[3] += r3;
            psq[0] += r0 * r0; psq[1] += r1 * r1; psq[2] += r2 * r2; psq[3] += r3 * r3;
        }
    }

    // ---- BN partial sums: reduce across the 4 node-groups within the wave, then atomics
#pragma unroll
    for (int p = 0; p < 4; ++p) {
        psum[p] += __shfl_xor(psum[p], 16);
        psum[p] += __shfl_xor(psum[p], 32);
        psq[p] += __shfl_xor(psq[p], 16);
        psq[p] += __shfl_xor(psq[p], 32);
    }
    if (((tid >> 4) & 3) == 0) {
#pragma unroll
        for (int p = 0; p < 4; ++p) {
            unsafeAtomicAdd(&stats[jbase + p], psum[p]);
            unsafeAtomicAdd(&stats[64 + jbase + p], psq[p]);
        }
    }
}

// ---------------------------------------------------------------- BN-fold + FC
__global__ __launch_bounds__(256) void k_out(
        const float* __restrict__ r, const float* __restrict__ stats,
        const float* __restrict__ gamma, const float* __restrict__ beta,
        const float* __restrict__ Wfc, const float* __restrict__ bfc,
        float* __restrict__ out, int N) {
    __shared__ float sWm[64 * 16];
    __shared__ float sShift[64];
    __shared__ float sBase[16];
    const int tid = threadIdx.x;
    const float invN = 1.0f / (float)N;
    if (tid < 64) {
        float mu = stats[tid] * invN;
        float var = stats[64 + tid] * invN - mu * mu;
        float sc = gamma[tid] / sqrtf(var + 1e-5f);
        sShift[tid] = beta[tid] - mu * sc;
#pragma unroll
        for (int c = 0; c < 16; ++c) sWm[tid * 16 + c] = Wfc[c * 64 + tid] * sc;
    }
    __syncthreads();
    if (tid < 16) {
        float b = bfc[tid];
#pragma unroll
        for (int j = 0; j < 64; ++j) b += sShift[j] * Wfc[tid * 64 + j];
        sBase[tid] = b;
    }
    __syncthreads();
    int g = blockIdx.x * 256 + tid;
    int n = g >> 4;
    int c = g & 15;
    if (n >= N) return;
    const float4* r4 = (const float4*)(r + (size_t)n * 64);
    float acc = sBase[c];
#pragma unroll
    for (int jq = 0; jq < 16; ++jq) {
        float4 v = r4[jq];
        acc += v.x * sWm[(jq * 4 + 0) * 16 + c];
        acc += v.y * sWm[(jq * 4 + 1) * 16 + c];
        acc += v.z * sWm[(jq * 4 + 2) * 16 + c];
        acc += v.w * sWm[(jq * 4 + 3) * 16 + c];
    }
    out[(size_t)n * 16 + c] = acc;
}

extern "C" void kernel_launch(void* const* d_in, const int* in_sizes, int n_in,
                              void* d_out, int out_size, void* d_ws, size_t ws_size,
                              hipStream_t stream) {
    const int* eidx = (const int*)d_in[0];
    const float* x = (const float*)d_in[1];
    const float* Wl = (const float*)d_in[2];
    const float* bl = (const float*)d_in[3];
    const float* Wr = (const float*)d_in[4];
    const float* gamma = (const float*)d_in[5];
    const float* beta = (const float*)d_in[6];
    const float* Wfc = (const float*)d_in[7];
    const float* bfc = (const float*)d_in[8];
    float* out = (float*)d_out;

    const int E = in_sizes[0] / 2;
    const int N = in_sizes[1] / 64;

    float* sums = (float*)d_ws;                 // N*64, becomes h/r in-place
    float* cnt = sums + (size_t)N * 64;         // N
    float* stats = cnt + N;                     // 128

    size_t zero_bytes = ((size_t)N * 64 + (size_t)N + 128) * sizeof(float);
    hipMemsetAsync(d_ws, 0, zero_bytes, stream);

    int sblocks = (E * 16 + 255) / 256;
    k_scatter<<<sblocks, 256, 0, stream>>>(eidx, (const float4*)x, sums, cnt, E);

    int fblocks = (N + 63) / 64;
    k_fused<<<fblocks, 256, 0, stream>>>(x, Wl, bl, Wr, sums, cnt, stats, N);

    int oblocks = (int)(((size_t)N * 16 + 255) / 256);
    k_out<<<oblocks, 256, 0, stream>>>(sums, stats, gamma, beta, Wfc, bfc, out, N);
}

// Round 2
// 1077.922 us; speedup vs baseline: 1.6718x; 1.6718x over previous
//
#include <hip/hip_runtime.h>
#include <hip/hip_bf16.h>

// SAGEConv(mean) via CSR-gather + fused [mean|x]@[Wl;Wr]^T + L2norm + ReLU
// + BN(train stats) + FC.  N=100000, E=1200000, F=H=64, C=16.
//
// ws layout (4B units):
//   [degcur: N int][stats: 128 f32][rowptr: N+1 int][col: E int][h: N*64 bf16]
// Only degcur+stats need zeroing (one small memset).

__device__ __forceinline__ int swz(int row, int col) {
    // 128x64 tile, rotate columns by 4*row: k-loop reads stay conflict-free
    return (row << 6) + ((col + ((row << 2) & 63)) & 63);
}

__device__ __forceinline__ unsigned short f2bf(float f) {
    unsigned int u = __builtin_bit_cast(unsigned int, f);
    u += 0x7FFFu + ((u >> 16) & 1u);
    return (unsigned short)(u >> 16);
}
__device__ __forceinline__ float bf2f(unsigned short s) {
    return __builtin_bit_cast(float, ((unsigned int)s) << 16);
}

// ---------------------------------------------------------------- degree hist
__global__ __launch_bounds__(256) void k_hist(const int* __restrict__ eidx,
                                              int* __restrict__ deg, int E) {
    int t = blockIdx.x * 256 + threadIdx.x;
    if (t < E) atomicAdd(&deg[eidx[E + t]], 1);
}

// --------------------------------------- single-block exclusive scan (8/thread)
__global__ __launch_bounds__(1024) void k_scan(int* __restrict__ degcur,
                                               int* __restrict__ rowptr, int N, int E) {
    __shared__ int s[1024];
    __shared__ int s_carry;
    const int tid = threadIdx.x;
    if (tid == 0) s_carry = 0;
    __syncthreads();
    for (int base = 0; base < N; base += 8192) {
        int idx = base + tid * 8;
        int v[8];
        int tsum = 0;
#pragma unroll
        for (int p = 0; p < 8; ++p) {
            int i = idx + p;
            v[p] = (i < N) ? degcur[i] : 0;
            tsum += v[p];
        }
        s[tid] = tsum;
        __syncthreads();
        for (int off = 1; off < 1024; off <<= 1) {
            int t = (tid >= off) ? s[tid - off] : 0;
            __syncthreads();
            s[tid] += t;
            __syncthreads();
        }
        int carry_in = s_carry;
        int run = s[tid] - tsum + carry_in;
#pragma unroll
        for (int p = 0; p < 8; ++p) {
            int i = idx + p;
            if (i < N) { rowptr[i] = run; degcur[i] = run; }  // degcur becomes cursor
            run += v[p];
        }
        __syncthreads();
        if (tid == 0) s_carry = carry_in + s[1023];
        __syncthreads();
    }
    if (tid == 0) rowptr[N] = E;
}

// ---------------------------------------------------------------- CSR fill
__global__ __launch_bounds__(256) void k_fill(const int* __restrict__ eidx,
                                              int* __restrict__ cursor,
                                              int* __restrict__ colv, int E) {
    int t = blockIdx.x * 256 + threadIdx.x;
    if (t < E) {
        int p = atomicAdd(&cursor[eidx[E + t]], 1);
        colv[p] = eidx[t];
    }
}

// --------- fused: gather-mean + [mean|x]@[Wl;Wr]^T + bl, L2norm, ReLU, BN stats
__global__ __launch_bounds__(256) void k_fused(
        const float4* __restrict__ x4,
        const float* __restrict__ Wl, const float* __restrict__ bl,
        const float* __restrict__ Wr,
        const int* __restrict__ rowptr, const int* __restrict__ colv,
        unsigned short* __restrict__ hout,   // N*64 bf16
        float* __restrict__ stats, int N) {
    __shared__ float sW[128 * 64];   // sW[k][j], swizzled
    __shared__ float sA[128 * 64];   // sA[k][n]: rows 0..63 = mean, 64..127 = x

    const int tid = threadIdx.x;
    const int n0 = blockIdx.x * 64;

    // stage weights
    for (int i = tid; i < 64 * 64; i += 256) {
        int j = i >> 6, k = i & 63;
        sW[swz(k, j)] = Wl[i];
        sW[swz(k + 64, j)] = Wr[i];
    }

    // gather-mean + stage A: 16-lane group owns a node row, lane = feature quad
    const int lane = tid & 15;
    const int grp = tid >> 4;
    for (int q = 0; q < 4; ++q) {
        int nl = grp * 4 + q;
        int n = n0 + nl;
        float4 am = make_float4(0.f, 0.f, 0.f, 0.f);
        float4 ax = am;
        if (n < N) {
            int b = rowptr[n], e = rowptr[n + 1];
            for (int p = b; p < e; ++p) {
                int srcn = colv[p];
                float4 v = x4[(size_t)srcn * 16 + lane];
                am.x += v.x; am.y += v.y; am.z += v.z; am.w += v.w;
            }
            float inv = 1.0f / fmaxf((float)(e - b), 1.0f);
            am.x *= inv; am.y *= inv; am.z *= inv; am.w *= inv;
            ax = x4[(size_t)n * 16 + lane];
        }
        int f0 = lane * 4;
        sA[swz(f0 + 0, nl)] = am.x;
        sA[swz(f0 + 1, nl)] = am.y;
        sA[swz(f0 + 2, nl)] = am.z;
        sA[swz(f0 + 3, nl)] = am.w;
        sA[swz(f0 + 64, nl)] = ax.x;
        sA[swz(f0 + 65, nl)] = ax.y;
        sA[swz(f0 + 66, nl)] = ax.z;
        sA[swz(f0 + 67, nl)] = ax.w;
    }
    __syncthreads();

    // register-tiled GEMM: thread = 4 nodes x 4 features
    const int jbase = (tid & 15) * 4;
    const int nb = ((tid >> 4) & 3) * 4 + (tid >> 6) * 16;
    float acc[4][4] = {};
#pragma unroll 4
    for (int k = 0; k < 128; ++k) {
        const int rot = (k << 2) & 63;
        float4 a = *(const float4*)(sA + (k << 6) + ((nb + rot) & 63));
        float4 w = *(const float4*)(sW + (k << 6) + ((jbase + rot) & 63));
        acc[0][0] += a.x * w.x; acc[0][1] += a.x * w.y; acc[0][2] += a.x * w.z; acc[0][3] += a.x * w.w;
        acc[1][0] += a.y * w.x; acc[1][1] += a.y * w.y; acc[1][2] += a.y * w.z; acc[1][3] += a.y * w.w;
        acc[2][0] += a.z * w.x; acc[2][1] += a.z * w.y; acc[2][2] += a.z * w.z; acc[2][3] += a.z * w.w;
        acc[3][0] += a.w * w.x; acc[3][1] += a.w * w.y; acc[3][2] += a.w * w.z; acc[3][3] += a.w * w.w;
    }

    // epilogue: +bias, L2-normalize row (16-lane group), ReLU, bf16 store, BN stats
    float4 blv = *(const float4*)(bl + jbase);
    float psum[4] = {0.f, 0.f, 0.f, 0.f};
    float psq[4] = {0.f, 0.f, 0.f, 0.f};
#pragma unroll
    for (int q = 0; q < 4; ++q) {
        float h0 = acc[q][0] + blv.x;
        float h1 = acc[q][1] + blv.y;
        float h2 = acc[q][2] + blv.z;
        float h3 = acc[q][3] + blv.w;
        float ss = h0 * h0 + h1 * h1 + h2 * h2 + h3 * h3;
        ss += __shfl_xor(ss, 1);
        ss += __shfl_xor(ss, 2);
        ss += __shfl_xor(ss, 4);
        ss += __shfl_xor(ss, 8);
        float sc = 1.0f / fmaxf(sqrtf(ss), 1e-12f);
        float r0 = fmaxf(h0 * sc, 0.f);
        float r1 = fmaxf(h1 * sc, 0.f);
        float r2 = fmaxf(h2 * sc, 0.f);
        float r3 = fmaxf(h3 * sc, 0.f);
        unsigned short b0 = f2bf(r0), b1 = f2bf(r1), b2 = f2bf(r2), b3 = f2bf(r3);
        // stats from the rounded values so BN is self-consistent with stored h
        float e0 = bf2f(b0), e1 = bf2f(b1), e2 = bf2f(b2), e3 = bf2f(b3);
        int n = n0 + nb + q;
        if (n < N) {
            ushort4 pk = make_ushort4(b0, b1, b2, b3);
            *(ushort4*)(hout + (size_t)n * 64 + jbase) = pk;
            psum[0] += e0; psum[1] += e1; psum[2] += e2; psum[3] += e3;
            psq[0] += e0 * e0; psq[1] += e1 * e1; psq[2] += e2 * e2; psq[3] += e3 * e3;
        }
    }

#pragma unroll
    for (int p = 0; p < 4; ++p) {
        psum[p] += __shfl_xor(psum[p], 16);
        psum[p] += __shfl_xor(psum[p], 32);
        psq[p] += __shfl_xor(psq[p], 16);
        psq[p] += __shfl_xor(psq[p], 32);
    }
    if (((tid >> 4) & 3) == 0) {
#pragma unroll
        for (int p = 0; p < 4; ++p) {
            unsafeAtomicAdd(&stats[jbase + p], psum[p]);
            unsafeAtomicAdd(&stats[64 + jbase + p], psq[p]);
        }
    }
}

// ---------------------------------------------------------------- BN-fold + FC
__global__ __launch_bounds__(256) void k_out(
        const unsigned short* __restrict__ h, const float* __restrict__ stats,
        const float* __restrict__ gamma, const float* __restrict__ beta,
        const float* __restrict__ Wfc, const float* __restrict__ bfc,
        float* __restrict__ out, int N) {
    __shared__ float sWm[64 * 16];
    __shared__ float sShift[64];
    __shared__ float sBase[16];
    const int tid = threadIdx.x;
    const float invN = 1.0f / (float)N;
    if (tid < 64) {
        float mu = stats[tid] * invN;
        float var = stats[64 + tid] * invN - mu * mu;
        float sc = gamma[tid] / sqrtf(var + 1e-5f);
        sShift[tid] = beta[tid] - mu * sc;
#pragma unroll
        for (int c = 0; c < 16; ++c) sWm[tid * 16 + c] = Wfc[c * 64 + tid] * sc;
    }
    __syncthreads();
    if (tid < 16) {
        float b = bfc[tid];
#pragma unroll
        for (int j = 0; j < 64; ++j) b += sShift[j] * Wfc[tid * 64 + j];
        sBase[tid] = b;
    }
    __syncthreads();
    int g = blockIdx.x * 256 + tid;
    int n = g >> 4;
    int c = g & 15;
    if (n >= N) return;
    const ushort4* h4 = (const ushort4*)(h + (size_t)n * 64);
    float acc = sBase[c];
#pragma unroll
    for (int jq = 0; jq < 16; ++jq) {
        ushort4 v = h4[jq];
        acc += bf2f(v.x) * sWm[(jq * 4 + 0) * 16 + c];
        acc += bf2f(v.y) * sWm[(jq * 4 + 1) * 16 + c];
        acc += bf2f(v.z) * sWm[(jq * 4 + 2) * 16 + c];
        acc += bf2f(v.w) * sWm[(jq * 4 + 3) * 16 + c];
    }
    out[(size_t)n * 16 + c] = acc;
}

extern "C" void kernel_launch(void* const* d_in, const int* in_sizes, int n_in,
                              void* d_out, int out_size, void* d_ws, size_t ws_size,
                              hipStream_t stream) {
    const int* eidx = (const int*)d_in[0];
    const float* x = (const float*)d_in[1];
    const float* Wl = (const float*)d_in[2];
    const float* bl = (const float*)d_in[3];
    const float* Wr = (const float*)d_in[4];
    const float* gamma = (const float*)d_in[5];
    const float* beta = (const float*)d_in[6];
    const float* Wfc = (const float*)d_in[7];
    const float* bfc = (const float*)d_in[8];
    float* out = (float*)d_out;

    const int E = in_sizes[0] / 2;
    const int N = in_sizes[1] / 64;

    int* degcur = (int*)d_ws;                                  // N
    float* stats = (float*)(degcur + N);                       // 128
    int* rowptr = (int*)(stats + 128);                         // N+1
    int* colv = rowptr + (N + 1);                              // E
    unsigned short* h = (unsigned short*)(colv + E);           // N*64 bf16

    hipMemsetAsync(d_ws, 0, (size_t)(N + 128) * 4, stream);

    int eblocks = (E + 255) / 256;
    k_hist<<<eblocks, 256, 0, stream>>>(eidx, degcur, E);
    k_scan<<<1, 1024, 0, stream>>>(degcur, rowptr, N, E);
    k_fill<<<eblocks, 256, 0, stream>>>(eidx, degcur, colv, E);

    int fblocks = (N + 63) / 64;
    k_fused<<<fblocks, 256, 0, stream>>>((const float4*)x, Wl, bl, Wr,
                                         rowptr, colv, h, stats, N);

    int oblocks = (int)(((size_t)N * 16 + 255) / 256);
    k_out<<<oblocks, 256, 0, stream>>>(h, stats, gamma, beta, Wfc, bfc, out, N);
}

// Round 3
// 1057.242 us; speedup vs baseline: 1.7045x; 1.0196x over previous
//
#include <hip/hip_runtime.h>
#include <hip/hip_bf16.h>

// SAGEConv(mean) via CSR + dedicated high-occupancy gather kernel, then fused
// [mean|x]@[Wl;Wr]^T + L2norm + ReLU + BN(train stats) + FC.
// N=100000, E=1200000, F=H=64, C=16.
//
// ws layout (4B words): [degcur: N][stats: 128 f32][rowptr: N+1][colv: E]
//                       [mh: N*32  (bf16 mean, later overwritten in-place by h)]
// mh aliasing is safe: k_fused reads mean for its own 64-node tile before the
// barrier, writes h for the same tile after — block-private range, no cross-block
// hazard. Only degcur+stats need zeroing.

__device__ __forceinline__ int swz(int row, int col) {
    return (row << 6) + ((col + ((row << 2) & 63)) & 63);
}

__device__ __forceinline__ unsigned short f2bf(float f) {
    unsigned int u = __builtin_bit_cast(unsigned int, f);
    u += 0x7FFFu + ((u >> 16) & 1u);
    return (unsigned short)(u >> 16);
}
__device__ __forceinline__ float bf2f(unsigned short s) {
    return __builtin_bit_cast(float, ((unsigned int)s) << 16);
}

// ---------------------------------------------------------------- degree hist
__global__ __launch_bounds__(256) void k_hist(const int* __restrict__ eidx,
                                              int* __restrict__ deg, int E) {
    int t = blockIdx.x * 256 + threadIdx.x;
    if (t < E) atomicAdd(&deg[eidx[E + t]], 1);
}

// --------------------------------------- single-block exclusive scan (8/thread)
__global__ __launch_bounds__(1024) void k_scan(int* __restrict__ degcur,
                                               int* __restrict__ rowptr, int N, int E) {
    __shared__ int s[1024];
    __shared__ int s_carry;
    const int tid = threadIdx.x;
    if (tid == 0) s_carry = 0;
    __syncthreads();
    for (int base = 0; base < N; base += 8192) {
        int idx = base + tid * 8;
        int v[8];
        int tsum = 0;
#pragma unroll
        for (int p = 0; p < 8; ++p) {
            int i = idx + p;
            v[p] = (i < N) ? degcur[i] : 0;
            tsum += v[p];
        }
        s[tid] = tsum;
        __syncthreads();
        for (int off = 1; off < 1024; off <<= 1) {
            int t = (tid >= off) ? s[tid - off] : 0;
            __syncthreads();
            s[tid] += t;
            __syncthreads();
        }
        int carry_in = s_carry;
        int run = s[tid] - tsum + carry_in;
#pragma unroll
        for (int p = 0; p < 8; ++p) {
            int i = idx + p;
            if (i < N) { rowptr[i] = run; degcur[i] = run; }  // degcur -> cursor
            run += v[p];
        }
        __syncthreads();
        if (tid == 0) s_carry = carry_in + s[1023];
        __syncthreads();
    }
    if (tid == 0) rowptr[N] = E;
}

// ---------------------------------------------------------------- CSR fill
__global__ __launch_bounds__(256) void k_fill(const int* __restrict__ eidx,
                                              int* __restrict__ cursor,
                                              int* __restrict__ colv, int E) {
    int t = blockIdx.x * 256 + threadIdx.x;
    if (t < E) {
        int p = atomicAdd(&cursor[eidx[E + t]], 1);
        colv[p] = eidx[t];
    }
}

// ------------------------------- gather-mean: 16 lanes/node, full occupancy
__global__ __launch_bounds__(256) void k_gather(
        const float4* __restrict__ x4, const int* __restrict__ rowptr,
        const int* __restrict__ colv, ushort4* __restrict__ mh, int N) {
    int t = blockIdx.x * 256 + threadIdx.x;
    int n = t >> 4;
    int l = t & 15;
    if (n >= N) return;
    int b = rowptr[n], e = rowptr[n + 1];
    float ax = 0.f, ay = 0.f, az = 0.f, aw = 0.f;
    int p = b;
    for (; p + 2 <= e; p += 2) {
        int s0 = colv[p];
        int s1 = colv[p + 1];
        float4 v0 = x4[(size_t)s0 * 16 + l];
        float4 v1 = x4[(size_t)s1 * 16 + l];
        ax += v0.x + v1.x; ay += v0.y + v1.y;
        az += v0.z + v1.z; aw += v0.w + v1.w;
    }
    if (p < e) {
        int s0 = colv[p];
        float4 v0 = x4[(size_t)s0 * 16 + l];
        ax += v0.x; ay += v0.y; az += v0.z; aw += v0.w;
    }
    float inv = 1.0f / fmaxf((float)(e - b), 1.0f);
    mh[(size_t)n * 16 + l] = make_ushort4(f2bf(ax * inv), f2bf(ay * inv),
                                          f2bf(az * inv), f2bf(aw * inv));
}

// --------- fused: [mean|x]@[Wl;Wr]^T + bl, L2norm, ReLU, BN stats; h over mh
__global__ __launch_bounds__(256) void k_fused(
        const float4* __restrict__ x4,
        const float* __restrict__ Wl, const float* __restrict__ bl,
        const float* __restrict__ Wr,
        unsigned short* __restrict__ mh,   // in: bf16 mean; out: bf16 h (same tile)
        float* __restrict__ stats, int N) {
    __shared__ float sW[128 * 64];
    __shared__ float sA[128 * 64];

    const int tid = threadIdx.x;
    const int n0 = blockIdx.x * 64;

    for (int i = tid; i < 64 * 64; i += 256) {
        int j = i >> 6, k = i & 63;
        sW[swz(k, j)] = Wl[i];
        sW[swz(k + 64, j)] = Wr[i];
    }

    const int lane = tid & 15;
    const int grp = tid >> 4;
#pragma unroll
    for (int q = 0; q < 4; ++q) {
        int nl = grp * 4 + q;
        int n = n0 + nl;
        float4 am = make_float4(0.f, 0.f, 0.f, 0.f);
        float4 ax = am;
        if (n < N) {
            ushort4 mv = *(const ushort4*)(mh + (size_t)n * 64 + lane * 4);
            am = make_float4(bf2f(mv.x), bf2f(mv.y), bf2f(mv.z), bf2f(mv.w));
            ax = x4[(size_t)n * 16 + lane];
        }
        int f0 = lane * 4;
        sA[swz(f0 + 0, nl)] = am.x;
        sA[swz(f0 + 1, nl)] = am.y;
        sA[swz(f0 + 2, nl)] = am.z;
        sA[swz(f0 + 3, nl)] = am.w;
        sA[swz(f0 + 64, nl)] = ax.x;
        sA[swz(f0 + 65, nl)] = ax.y;
        sA[swz(f0 + 66, nl)] = ax.z;
        sA[swz(f0 + 67, nl)] = ax.w;
    }
    __syncthreads();

    const int jbase = (tid & 15) * 4;
    const int nb = ((tid >> 4) & 3) * 4 + (tid >> 6) * 16;
    float acc[4][4] = {};
#pragma unroll 4
    for (int k = 0; k < 128; ++k) {
        const int rot = (k << 2) & 63;
        float4 a = *(const float4*)(sA + (k << 6) + ((nb + rot) & 63));
        float4 w = *(const float4*)(sW + (k << 6) + ((jbase + rot) & 63));
        acc[0][0] += a.x * w.x; acc[0][1] += a.x * w.y; acc[0][2] += a.x * w.z; acc[0][3] += a.x * w.w;
        acc[1][0] += a.y * w.x; acc[1][1] += a.y * w.y; acc[1][2] += a.y * w.z; acc[1][3] += a.y * w.w;
        acc[2][0] += a.z * w.x; acc[2][1] += a.z * w.y; acc[2][2] += a.z * w.z; acc[2][3] += a.z * w.w;
        acc[3][0] += a.w * w.x; acc[3][1] += a.w * w.y; acc[3][2] += a.w * w.z; acc[3][3] += a.w * w.w;
    }

    float4 blv = *(const float4*)(bl + jbase);
    float psum[4] = {0.f, 0.f, 0.f, 0.f};
    float psq[4] = {0.f, 0.f, 0.f, 0.f};
#pragma unroll
    for (int q = 0; q < 4; ++q) {
        float h0 = acc[q][0] + blv.x;
        float h1 = acc[q][1] + blv.y;
        float h2 = acc[q][2] + blv.z;
        float h3 = acc[q][3] + blv.w;
        float ss = h0 * h0 + h1 * h1 + h2 * h2 + h3 * h3;
        ss += __shfl_xor(ss, 1);
        ss += __shfl_xor(ss, 2);
        ss += __shfl_xor(ss, 4);
        ss += __shfl_xor(ss, 8);
        float sc = 1.0f / fmaxf(sqrtf(ss), 1e-12f);
        float r0 = fmaxf(h0 * sc, 0.f);
        float r1 = fmaxf(h1 * sc, 0.f);
        float r2 = fmaxf(h2 * sc, 0.f);
        float r3 = fmaxf(h3 * sc, 0.f);
        unsigned short b0 = f2bf(r0), b1 = f2bf(r1), b2 = f2bf(r2), b3 = f2bf(r3);
        float e0 = bf2f(b0), e1 = bf2f(b1), e2 = bf2f(b2), e3 = bf2f(b3);
        int n = n0 + nb + q;
        if (n < N) {
            *(ushort4*)(mh + (size_t)n * 64 + jbase) = make_ushort4(b0, b1, b2, b3);
            psum[0] += e0; psum[1] += e1; psum[2] += e2; psum[3] += e3;
            psq[0] += e0 * e0; psq[1] += e1 * e1; psq[2] += e2 * e2; psq[3] += e3 * e3;
        }
    }

#pragma unroll
    for (int p = 0; p < 4; ++p) {
        psum[p] += __shfl_xor(psum[p], 16);
        psum[p] += __shfl_xor(psum[p], 32);
        psq[p] += __shfl_xor(psq[p], 16);
        psq[p] += __shfl_xor(psq[p], 32);
    }
    if (((tid >> 4) & 3) == 0) {
#pragma unroll
        for (int p = 0; p < 4; ++p) {
            unsafeAtomicAdd(&stats[jbase + p], psum[p]);
            unsafeAtomicAdd(&stats[64 + jbase + p], psq[p]);
        }
    }
}

// ---------------------------------------------------------------- BN-fold + FC
__global__ __launch_bounds__(256) void k_out(
        const unsigned short* __restrict__ h, const float* __restrict__ stats,
        const float* __restrict__ gamma, const float* __restrict__ beta,
        const float* __restrict__ Wfc, const float* __restrict__ bfc,
        float* __restrict__ out, int N) {
    __shared__ float sWm[64 * 16];
    __shared__ float sShift[64];
    __shared__ float sBase[16];
    const int tid = threadIdx.x;
    const float invN = 1.0f / (float)N;
    if (tid < 64) {
        float mu = stats[tid] * invN;
        float var = stats[64 + tid] * invN - mu * mu;
        float sc = gamma[tid] / sqrtf(var + 1e-5f);
        sShift[tid] = beta[tid] - mu * sc;
#pragma unroll
        for (int c = 0; c < 16; ++c) sWm[tid * 16 + c] = Wfc[c * 64 + tid] * sc;
    }
    __syncthreads();
    if (tid < 16) {
        float b = bfc[tid];
#pragma unroll
        for (int j = 0; j < 64; ++j) b += sShift[j] * Wfc[tid * 64 + j];
        sBase[tid] = b;
    }
    __syncthreads();
    int g = blockIdx.x * 256 + tid;
    int n = g >> 4;
    int c = g & 15;
    if (n >= N) return;
    const ushort4* h4 = (const ushort4*)(h + (size_t)n * 64);
    float acc = sBase[c];
#pragma unroll
    for (int jq = 0; jq < 16; ++jq) {
        ushort4 v = h4[jq];
        acc += bf2f(v.x) * sWm[(jq * 4 + 0) * 16 + c];
        acc += bf2f(v.y) * sWm[(jq * 4 + 1) * 16 + c];
        acc += bf2f(v.z) * sWm[(jq * 4 + 2) * 16 + c];
        acc += bf2f(v.w) * sWm[(jq * 4 + 3) * 16 + c];
    }
    out[(size_t)n * 16 + c] = acc;
}

extern "C" void kernel_launch(void* const* d_in, const int* in_sizes, int n_in,
                              void* d_out, int out_size, void* d_ws, size_t ws_size,
                              hipStream_t stream) {
    const int* eidx = (const int*)d_in[0];
    const float* x = (const float*)d_in[1];
    const float* Wl = (const float*)d_in[2];
    const float* bl = (const float*)d_in[3];
    const float* Wr = (const float*)d_in[4];
    const float* gamma = (const float*)d_in[5];
    const float* beta = (const float*)d_in[6];
    const float* Wfc = (const float*)d_in[7];
    const float* bfc = (const float*)d_in[8];
    float* out = (float*)d_out;

    const int E = in_sizes[0] / 2;
    const int N = in_sizes[1] / 64;

    int* degcur = (int*)d_ws;                                  // N
    float* stats = (float*)(degcur + N);                       // 128
    int* rowptr = (int*)(stats + 128);                         // N+1
    int* colv = rowptr + (N + 1);                              // E
    unsigned short* mh = (unsigned short*)(colv + E);          // N*64 bf16 (mean -> h)

    hipMemsetAsync(d_ws, 0, (size_t)(N + 128) * 4, stream);

    int eblocks = (E + 255) / 256;
    k_hist<<<eblocks, 256, 0, stream>>>(eidx, degcur, E);
    k_scan<<<1, 1024, 0, stream>>>(degcur, rowptr, N, E);
    k_fill<<<eblocks, 256, 0, stream>>>(eidx, degcur, colv, E);

    int gblocks = (int)(((size_t)N * 16 + 255) / 256);
    k_gather<<<gblocks, 256, 0, stream>>>((const float4*)x, rowptr, colv,
                                          (ushort4*)mh, N);

    int fblocks = (N + 63) / 64;
    k_fused<<<fblocks, 256, 0, stream>>>((const float4*)x, Wl, bl, Wr,
                                         mh, stats, N);

    int oblocks = (int)(((size_t)N * 16 + 255) / 256);
    k_out<<<oblocks, 256, 0, stream>>>(mh, stats, gamma, beta, Wfc, bfc, out, N);
}

// Round 4
// 500.488 us; speedup vs baseline: 3.6007x; 2.1124x over previous
//
#include <hip/hip_runtime.h>
#include <hip/hip_bf16.h>

// SAGEConv(mean) via CSR + gather kernel + fused GEMM/L2norm/ReLU/BN-stats
// (atomic-free partials) + stats-reduce + BN-fold FC.
// N=100000, E=1200000, F=H=64, C=16.
//
// ws layout (4B words):
//   [degcur: N][rowptr: N+1][colv: E][mh: N*32 (bf16 mean->h)]
//   [pstats: fblocks*128][stats: 128]
// Only degcur needs zeroing. BN stats flow: per-block partials (no atomics!)
// -> k_stats tree reduce. The old atomic version hammered 800k f32 RMWs onto
// 4 cache lines from 8 XCDs ==> ~600us serialization. Never again.

__device__ __forceinline__ int swz(int row, int col) {
    return (row << 6) + ((col + ((row << 2) & 63)) & 63);
}

__device__ __forceinline__ unsigned short f2bf(float f) {
    unsigned int u = __builtin_bit_cast(unsigned int, f);
    u += 0x7FFFu + ((u >> 16) & 1u);
    return (unsigned short)(u >> 16);
}
__device__ __forceinline__ float bf2f(unsigned short s) {
    return __builtin_bit_cast(float, ((unsigned int)s) << 16);
}

// ---------------------------------------------------------------- degree hist
__global__ __launch_bounds__(256) void k_hist(const int* __restrict__ eidx,
                                              int* __restrict__ deg, int E) {
    int t = blockIdx.x * 256 + threadIdx.x;
    if (t < E) atomicAdd(&deg[eidx[E + t]], 1);
}

// --------------------------------------- single-block exclusive scan (8/thread)
__global__ __launch_bounds__(1024) void k_scan(int* __restrict__ degcur,
                                               int* __restrict__ rowptr, int N, int E) {
    __shared__ int s[1024];
    __shared__ int s_carry;
    const int tid = threadIdx.x;
    if (tid == 0) s_carry = 0;
    __syncthreads();
    for (int base = 0; base < N; base += 8192) {
        int idx = base + tid * 8;
        int v[8];
        int tsum = 0;
#pragma unroll
        for (int p = 0; p < 8; ++p) {
            int i = idx + p;
            v[p] = (i < N) ? degcur[i] : 0;
            tsum += v[p];
        }
        s[tid] = tsum;
        __syncthreads();
        for (int off = 1; off < 1024; off <<= 1) {
            int t = (tid >= off) ? s[tid - off] : 0;
            __syncthreads();
            s[tid] += t;
            __syncthreads();
        }
        int carry_in = s_carry;
        int run = s[tid] - tsum + carry_in;
#pragma unroll
        for (int p = 0; p < 8; ++p) {
            int i = idx + p;
            if (i < N) { rowptr[i] = run; degcur[i] = run; }  // degcur -> cursor
            run += v[p];
        }
        __syncthreads();
        if (tid == 0) s_carry = carry_in + s[1023];
        __syncthreads();
    }
    if (tid == 0) rowptr[N] = E;
}

// ---------------------------------------------------------------- CSR fill
__global__ __launch_bounds__(256) void k_fill(const int* __restrict__ eidx,
                                              int* __restrict__ cursor,
                                              int* __restrict__ colv, int E) {
    int t = blockIdx.x * 256 + threadIdx.x;
    if (t < E) {
        int p = atomicAdd(&cursor[eidx[E + t]], 1);
        colv[p] = eidx[t];
    }
}

// ------------------------------- gather-mean: 16 lanes/node, full occupancy
__global__ __launch_bounds__(256) void k_gather(
        const float4* __restrict__ x4, const int* __restrict__ rowptr,
        const int* __restrict__ colv, ushort4* __restrict__ mh, int N) {
    int t = blockIdx.x * 256 + threadIdx.x;
    int n = t >> 4;
    int l = t & 15;
    if (n >= N) return;
    int b = rowptr[n], e = rowptr[n + 1];
    float ax = 0.f, ay = 0.f, az = 0.f, aw = 0.f;
    int p = b;
    for (; p + 4 <= e; p += 4) {
        int s0 = colv[p], s1 = colv[p + 1], s2 = colv[p + 2], s3 = colv[p + 3];
        float4 v0 = x4[(size_t)s0 * 16 + l];
        float4 v1 = x4[(size_t)s1 * 16 + l];
        float4 v2 = x4[(size_t)s2 * 16 + l];
        float4 v3 = x4[(size_t)s3 * 16 + l];
        ax += (v0.x + v1.x) + (v2.x + v3.x);
        ay += (v0.y + v1.y) + (v2.y + v3.y);
        az += (v0.z + v1.z) + (v2.z + v3.z);
        aw += (v0.w + v1.w) + (v2.w + v3.w);
    }
    for (; p < e; ++p) {
        int s0 = colv[p];
        float4 v0 = x4[(size_t)s0 * 16 + l];
        ax += v0.x; ay += v0.y; az += v0.z; aw += v0.w;
    }
    float inv = 1.0f / fmaxf((float)(e - b), 1.0f);
    mh[(size_t)n * 16 + l] = make_ushort4(f2bf(ax * inv), f2bf(ay * inv),
                                          f2bf(az * inv), f2bf(aw * inv));
}

// --------- fused: [mean|x]@[Wl;Wr]^T + bl, L2norm, ReLU, BN partials; h over mh
__global__ __launch_bounds__(256) void k_fused(
        const float4* __restrict__ x4,
        const float* __restrict__ Wl, const float* __restrict__ bl,
        const float* __restrict__ Wr,
        unsigned short* __restrict__ mh,   // in: bf16 mean; out: bf16 h
        float* __restrict__ pstats, int N) {
    __shared__ float sW[128 * 64];
    __shared__ float sA[128 * 64];
    __shared__ float sRed[4][128];

    const int tid = threadIdx.x;
    const int n0 = blockIdx.x * 64;

    for (int i = tid; i < 64 * 64; i += 256) {
        int j = i >> 6, k = i & 63;
        sW[swz(k, j)] = Wl[i];
        sW[swz(k + 64, j)] = Wr[i];
    }

    const int lane = tid & 15;
    const int grp = tid >> 4;
#pragma unroll
    for (int q = 0; q < 4; ++q) {
        int nl = grp * 4 + q;
        int n = n0 + nl;
        float4 am = make_float4(0.f, 0.f, 0.f, 0.f);
        float4 ax = am;
        if (n < N) {
            ushort4 mv = *(const ushort4*)(mh + (size_t)n * 64 + lane * 4);
            am = make_float4(bf2f(mv.x), bf2f(mv.y), bf2f(mv.z), bf2f(mv.w));
            ax = x4[(size_t)n * 16 + lane];
        }
        int f0 = lane * 4;
        sA[swz(f0 + 0, nl)] = am.x;
        sA[swz(f0 + 1, nl)] = am.y;
        sA[swz(f0 + 2, nl)] = am.z;
        sA[swz(f0 + 3, nl)] = am.w;
        sA[swz(f0 + 64, nl)] = ax.x;
        sA[swz(f0 + 65, nl)] = ax.y;
        sA[swz(f0 + 66, nl)] = ax.z;
        sA[swz(f0 + 67, nl)] = ax.w;
    }
    __syncthreads();

    const int jbase = (tid & 15) * 4;
    const int nb = ((tid >> 4) & 3) * 4 + (tid >> 6) * 16;
    float acc[4][4] = {};
#pragma unroll 4
    for (int k = 0; k < 128; ++k) {
        const int rot = (k << 2) & 63;
        float4 a = *(const float4*)(sA + (k << 6) + ((nb + rot) & 63));
        float4 w = *(const float4*)(sW + (k << 6) + ((jbase + rot) & 63));
        acc[0][0] += a.x * w.x; acc[0][1] += a.x * w.y; acc[0][2] += a.x * w.z; acc[0][3] += a.x * w.w;
        acc[1][0] += a.y * w.x; acc[1][1] += a.y * w.y; acc[1][2] += a.y * w.z; acc[1][3] += a.y * w.w;
        acc[2][0] += a.z * w.x; acc[2][1] += a.z * w.y; acc[2][2] += a.z * w.z; acc[2][3] += a.z * w.w;
        acc[3][0] += a.w * w.x; acc[3][1] += a.w * w.y; acc[3][2] += a.w * w.z; acc[3][3] += a.w * w.w;
    }

    float4 blv = *(const float4*)(bl + jbase);
    float psum[4] = {0.f, 0.f, 0.f, 0.f};
    float psq[4] = {0.f, 0.f, 0.f, 0.f};
#pragma unroll
    for (int q = 0; q < 4; ++q) {
        float h0 = acc[q][0] + blv.x;
        float h1 = acc[q][1] + blv.y;
        float h2 = acc[q][2] + blv.z;
        float h3 = acc[q][3] + blv.w;
        float ss = h0 * h0 + h1 * h1 + h2 * h2 + h3 * h3;
        ss += __shfl_xor(ss, 1);
        ss += __shfl_xor(ss, 2);
        ss += __shfl_xor(ss, 4);
        ss += __shfl_xor(ss, 8);
        float sc = 1.0f / fmaxf(sqrtf(ss), 1e-12f);
        float r0 = fmaxf(h0 * sc, 0.f);
        float r1 = fmaxf(h1 * sc, 0.f);
        float r2 = fmaxf(h2 * sc, 0.f);
        float r3 = fmaxf(h3 * sc, 0.f);
        unsigned short b0 = f2bf(r0), b1 = f2bf(r1), b2 = f2bf(r2), b3 = f2bf(r3);
        float e0 = bf2f(b0), e1 = bf2f(b1), e2 = bf2f(b2), e3 = bf2f(b3);
        int n = n0 + nb + q;
        if (n < N) {
            *(ushort4*)(mh + (size_t)n * 64 + jbase) = make_ushort4(b0, b1, b2, b3);
            psum[0] += e0; psum[1] += e1; psum[2] += e2; psum[3] += e3;
            psq[0] += e0 * e0; psq[1] += e1 * e1; psq[2] += e2 * e2; psq[3] += e3 * e3;
        }
    }

    // wave-level reduce across the 4 node-groups; lanes 0..15 hold features lane*4+p
#pragma unroll
    for (int p = 0; p < 4; ++p) {
        psum[p] += __shfl_xor(psum[p], 16);
        psum[p] += __shfl_xor(psum[p], 32);
        psq[p] += __shfl_xor(psq[p], 16);
        psq[p] += __shfl_xor(psq[p], 32);
    }
    const int wid = tid >> 6;
    if ((tid & 63) < 16) {
        const int l = tid & 15;
#pragma unroll
        for (int p = 0; p < 4; ++p) {
            sRed[wid][l * 4 + p] = psum[p];
            sRed[wid][64 + l * 4 + p] = psq[p];
        }
    }
    __syncthreads();
    if (tid < 128) {
        float v = sRed[0][tid] + sRed[1][tid] + sRed[2][tid] + sRed[3][tid];
        pstats[(size_t)blockIdx.x * 128 + tid] = v;
    }
}

// ---------------------------------------------- reduce per-block BN partials
__global__ __launch_bounds__(64) void k_stats(const float* __restrict__ pstats,
                                              float* __restrict__ stats, int nblk) {
    int col = blockIdx.x;     // 0..127
    int l = threadIdx.x;      // 0..63
    float s = 0.f;
    for (int r = l; r < nblk; r += 64) s += pstats[(size_t)r * 128 + col];
    s += __shfl_xor(s, 1);
    s += __shfl_xor(s, 2);
    s += __shfl_xor(s, 4);
    s += __shfl_xor(s, 8);
    s += __shfl_xor(s, 16);
    s += __shfl_xor(s, 32);
    if (l == 0) stats[col] = s;
}

// ---------------------------------------------------------------- BN-fold + FC
__global__ __launch_bounds__(256) void k_out(
        const unsigned short* __restrict__ h, const float* __restrict__ stats,
        const float* __restrict__ gamma, const float* __restrict__ beta,
        const float* __restrict__ Wfc, const float* __restrict__ bfc,
        float* __restrict__ out, int N) {
    __shared__ float sWm[64 * 16];
    __shared__ float sShift[64];
    __shared__ float sBase[16];
    const int tid = threadIdx.x;
    const float invN = 1.0f / (float)N;
    if (tid < 64) {
        float mu = stats[tid] * invN;
        float var = stats[64 + tid] * invN - mu * mu;
        float sc = gamma[tid] / sqrtf(var + 1e-5f);
        sShift[tid] = beta[tid] - mu * sc;
#pragma unroll
        for (int c = 0; c < 16; ++c) sWm[tid * 16 + c] = Wfc[c * 64 + tid] * sc;
    }
    __syncthreads();
    if (tid < 16) {
        float b = bfc[tid];
#pragma unroll
        for (int j = 0; j < 64; ++j) b += sShift[j] * Wfc[tid * 64 + j];
        sBase[tid] = b;
    }
    __syncthreads();
    int g = blockIdx.x * 256 + tid;
    int n = g >> 4;
    int c = g & 15;
    if (n >= N) return;
    const ushort4* h4 = (const ushort4*)(h + (size_t)n * 64);
    float acc = sBase[c];
#pragma unroll
    for (int jq = 0; jq < 16; ++jq) {
        ushort4 v = h4[jq];
        acc += bf2f(v.x) * sWm[(jq * 4 + 0) * 16 + c];
        acc += bf2f(v.y) * sWm[(jq * 4 + 1) * 16 + c];
        acc += bf2f(v.z) * sWm[(jq * 4 + 2) * 16 + c];
        acc += bf2f(v.w) * sWm[(jq * 4 + 3) * 16 + c];
    }
    out[(size_t)n * 16 + c] = acc;
}

extern "C" void kernel_launch(void* const* d_in, const int* in_sizes, int n_in,
                              void* d_out, int out_size, void* d_ws, size_t ws_size,
                              hipStream_t stream) {
    const int* eidx = (const int*)d_in[0];
    const float* x = (const float*)d_in[1];
    const float* Wl = (const float*)d_in[2];
    const float* bl = (const float*)d_in[3];
    const float* Wr = (const float*)d_in[4];
    const float* gamma = (const float*)d_in[5];
    const float* beta = (const float*)d_in[6];
    const float* Wfc = (const float*)d_in[7];
    const float* bfc = (const float*)d_in[8];
    float* out = (float*)d_out;

    const int E = in_sizes[0] / 2;
    const int N = in_sizes[1] / 64;
    const int fblocks = (N + 63) / 64;

    int* degcur = (int*)d_ws;                                  // N (zeroed)
    int* rowptr = degcur + N;                                  // N+1
    int* colv = rowptr + (N + 1);                              // E
    unsigned short* mh = (unsigned short*)(colv + E);          // N*64 bf16
    float* pstats = (float*)(mh + (size_t)N * 64);             // fblocks*128
    float* stats = pstats + (size_t)fblocks * 128;             // 128

    hipMemsetAsync(d_ws, 0, (size_t)N * 4, stream);

    int eblocks = (E + 255) / 256;
    k_hist<<<eblocks, 256, 0, stream>>>(eidx, degcur, E);
    k_scan<<<1, 1024, 0, stream>>>(degcur, rowptr, N, E);
    k_fill<<<eblocks, 256, 0, stream>>>(eidx, degcur, colv, E);

    int gblocks = (int)(((size_t)N * 16 + 255) / 256);
    k_gather<<<gblocks, 256, 0, stream>>>((const float4*)x, rowptr, colv,
                                          (ushort4*)mh, N);

    k_fused<<<fblocks, 256, 0, stream>>>((const float4*)x, Wl, bl, Wr,
                                         mh, pstats, N);

    k_stats<<<128, 64, 0, stream>>>(pstats, stats, fblocks);

    int oblocks = (int)(((size_t)N * 16 + 255) / 256);
    k_out<<<oblocks, 256, 0, stream>>>(mh, stats, gamma, beta, Wfc, bfc, out, N);
}

// Round 5
// 354.286 us; speedup vs baseline: 5.0865x; 1.4127x over previous
//
#include <hip/hip_runtime.h>
#include <hip/hip_bf16.h>

// SAGEConv(mean) via CSR (parallel 2-level scan) + bf16 gather + fused
// GEMM/L2norm/ReLU/BN-partials + stats-reduce + BN-fold FC.
// N=100000, E=1200000, F=H=64, C=16.
//
// ws layout (4B words):
//   [degcur: N][rowptr: N+1][colv: E][mh: N*32 (bf16 mean->h)]
//   [pstats: fblocks*128][stats: 128][bsum: 256][xbf: N*32 (bf16 x, optional)]
// Only degcur needs zeroing. BN stats via per-block partials + tree reduce
// (global same-address atomics cost ~600us cross-XCD — R4 lesson).
// Single-block scan cost 150us (R4) -> replaced by 2-level parallel scan.

__device__ __forceinline__ int swz(int row, int col) {
    return (row << 6) + ((col + ((row << 2) & 63)) & 63);
}

__device__ __forceinline__ unsigned short f2bf(float f) {
    unsigned int u = __builtin_bit_cast(unsigned int, f);
    u += 0x7FFFu + ((u >> 16) & 1u);
    return (unsigned short)(u >> 16);
}
__device__ __forceinline__ float bf2f(unsigned short s) {
    return __builtin_bit_cast(float, ((unsigned int)s) << 16);
}

// ---------------------------------------------------------------- degree hist
__global__ __launch_bounds__(256) void k_hist(const int* __restrict__ eidx,
                                              int* __restrict__ deg, int E) {
    int t = blockIdx.x * 256 + threadIdx.x;
    if (t < E) atomicAdd(&deg[eidx[E + t]], 1);
}

// ------------------------------------------- scan level 1: per-block local scan
// 256 threads x 4 items = 1024 elems/block. Writes local exclusive scan into
// rowptr and the block total into bsum[blk].
__global__ __launch_bounds__(256) void k_scan1(const int* __restrict__ deg,
                                               int* __restrict__ rowptr,
                                               int* __restrict__ bsum, int N) {
    __shared__ int swave[4];
    const int tid = threadIdx.x;
    const int base = blockIdx.x * 1024 + tid * 4;
    int v0 = (base + 0 < N) ? deg[base + 0] : 0;
    int v1 = (base + 1 < N) ? deg[base + 1] : 0;
    int v2 = (base + 2 < N) ? deg[base + 2] : 0;
    int v3 = (base + 3 < N) ? deg[base + 3] : 0;
    int tsum = v0 + v1 + v2 + v3;
    const int lane = tid & 63, wid = tid >> 6;
    int s = tsum;
#pragma unroll
    for (int off = 1; off < 64; off <<= 1) {
        int t = __shfl_up(s, off);
        if (lane >= off) s += t;
    }
    if (lane == 63) swave[wid] = s;
    __syncthreads();
    if (tid == 0) {
        int a = 0;
#pragma unroll
        for (int w = 0; w < 4; ++w) { int t = swave[w]; swave[w] = a; a += t; }
    }
    __syncthreads();
    int run = s - tsum + swave[wid];   // exclusive prefix for this thread
    if (base + 0 < N) rowptr[base + 0] = run; run += v0;
    if (base + 1 < N) rowptr[base + 1] = run; run += v1;
    if (base + 2 < N) rowptr[base + 2] = run; run += v2;
    if (base + 3 < N) rowptr[base + 3] = run;
    if (tid == 255) bsum[blockIdx.x] = swave[3] + s;   // block total
}

// ------------------------------------------- scan level 2: scan the block sums
__global__ __launch_bounds__(256) void k_scan2(int* __restrict__ bsum, int nblk) {
    __shared__ int s[256];
    int tid = threadIdx.x;
    int v = (tid < nblk) ? bsum[tid] : 0;
    s[tid] = v;
    __syncthreads();
    for (int off = 1; off < 256; off <<= 1) {
        int t = (tid >= off) ? s[tid - off] : 0;
        __syncthreads();
        s[tid] += t;
        __syncthreads();
    }
    if (tid < nblk) bsum[tid] = s[tid] - v;   // exclusive
}

// ----------------------------- scan level 3: add block offsets, emit cursor too
__global__ __launch_bounds__(256) void k_scan3(int* __restrict__ rowptr,
                                               const int* __restrict__ bsum,
                                               int* __restrict__ cursor, int N, int E) {
    const int tid = threadIdx.x;
    const int base = blockIdx.x * 1024 + tid * 4;
    const int off = bsum[blockIdx.x];
#pragma unroll
    for (int p = 0; p < 4; ++p) {
        int i = base + p;
        if (i < N) { int v = rowptr[i] + off; rowptr[i] = v; cursor[i] = v; }
    }
    if (blockIdx.x == 0 && tid == 0) rowptr[N] = E;
}

// ---------------------------------------------------------------- CSR fill
__global__ __launch_bounds__(256) void k_fill(const int* __restrict__ eidx,
                                              int* __restrict__ cursor,
                                              int* __restrict__ colv, int E) {
    int t = blockIdx.x * 256 + threadIdx.x;
    if (t < E) {
        int p = atomicAdd(&cursor[eidx[E + t]], 1);
        colv[p] = eidx[t];
    }
}

// ---------------------------------------------------------------- x -> bf16
__global__ __launch_bounds__(256) void k_xcast(const float4* __restrict__ x4,
                                               ushort4* __restrict__ xbf, int n4) {
    int t = blockIdx.x * 256 + threadIdx.x;
    if (t < n4) {
        float4 v = x4[t];
        xbf[t] = make_ushort4(f2bf(v.x), f2bf(v.y), f2bf(v.z), f2bf(v.w));
    }
}

// ------------------------- gather-mean (bf16 x): 16 lanes/node, full occupancy
__global__ __launch_bounds__(256) void k_gather_bf(
        const ushort4* __restrict__ xbf, const int* __restrict__ rowptr,
        const int* __restrict__ colv, ushort4* __restrict__ mh, int N) {
    int t = blockIdx.x * 256 + threadIdx.x;
    int n = t >> 4;
    int l = t & 15;
    if (n >= N) return;
    int b = rowptr[n], e = rowptr[n + 1];
    float ax = 0.f, ay = 0.f, az = 0.f, aw = 0.f;
    int p = b;
    for (; p + 4 <= e; p += 4) {
        int s0 = colv[p], s1 = colv[p + 1], s2 = colv[p + 2], s3 = colv[p + 3];
        ushort4 v0 = xbf[(size_t)s0 * 16 + l];
        ushort4 v1 = xbf[(size_t)s1 * 16 + l];
        ushort4 v2 = xbf[(size_t)s2 * 16 + l];
        ushort4 v3 = xbf[(size_t)s3 * 16 + l];
        ax += (bf2f(v0.x) + bf2f(v1.x)) + (bf2f(v2.x) + bf2f(v3.x));
        ay += (bf2f(v0.y) + bf2f(v1.y)) + (bf2f(v2.y) + bf2f(v3.y));
        az += (bf2f(v0.z) + bf2f(v1.z)) + (bf2f(v2.z) + bf2f(v3.z));
        aw += (bf2f(v0.w) + bf2f(v1.w)) + (bf2f(v2.w) + bf2f(v3.w));
    }
    for (; p < e; ++p) {
        int s0 = colv[p];
        ushort4 v0 = xbf[(size_t)s0 * 16 + l];
        ax += bf2f(v0.x); ay += bf2f(v0.y); az += bf2f(v0.z); aw += bf2f(v0.w);
    }
    float inv = 1.0f / fmaxf((float)(e - b), 1.0f);
    mh[(size_t)n * 16 + l] = make_ushort4(f2bf(ax * inv), f2bf(ay * inv),
                                          f2bf(az * inv), f2bf(aw * inv));
}

// ------------------------- gather-mean (f32 x fallback, if ws too small)
__global__ __launch_bounds__(256) void k_gather_f32(
        const float4* __restrict__ x4, const int* __restrict__ rowptr,
        const int* __restrict__ colv, ushort4* __restrict__ mh, int N) {
    int t = blockIdx.x * 256 + threadIdx.x;
    int n = t >> 4;
    int l = t & 15;
    if (n >= N) return;
    int b = rowptr[n], e = rowptr[n + 1];
    float ax = 0.f, ay = 0.f, az = 0.f, aw = 0.f;
    int p = b;
    for (; p + 4 <= e; p += 4) {
        int s0 = colv[p], s1 = colv[p + 1], s2 = colv[p + 2], s3 = colv[p + 3];
        float4 v0 = x4[(size_t)s0 * 16 + l];
        float4 v1 = x4[(size_t)s1 * 16 + l];
        float4 v2 = x4[(size_t)s2 * 16 + l];
        float4 v3 = x4[(size_t)s3 * 16 + l];
        ax += (v0.x + v1.x) + (v2.x + v3.x);
        ay += (v0.y + v1.y) + (v2.y + v3.y);
        az += (v0.z + v1.z) + (v2.z + v3.z);
        aw += (v0.w + v1.w) + (v2.w + v3.w);
    }
    for (; p < e; ++p) {
        int s0 = colv[p];
        float4 v0 = x4[(size_t)s0 * 16 + l];
        ax += v0.x; ay += v0.y; az += v0.z; aw += v0.w;
    }
    float inv = 1.0f / fmaxf((float)(e - b), 1.0f);
    mh[(size_t)n * 16 + l] = make_ushort4(f2bf(ax * inv), f2bf(ay * inv),
                                          f2bf(az * inv), f2bf(aw * inv));
}

// --------- fused: [mean|x]@[Wl;Wr]^T + bl, L2norm, ReLU, BN partials; h over mh
__global__ __launch_bounds__(256) void k_fused(
        const float4* __restrict__ x4,
        const float* __restrict__ Wl, const float* __restrict__ bl,
        const float* __restrict__ Wr,
        unsigned short* __restrict__ mh,   // in: bf16 mean; out: bf16 h
        float* __restrict__ pstats, int N) {
    __shared__ float sW[128 * 64];
    __shared__ float sA[128 * 64];
    __shared__ float sRed[4][128];

    const int tid = threadIdx.x;
    const int n0 = blockIdx.x * 64;

    for (int i = tid; i < 64 * 64; i += 256) {
        int j = i >> 6, k = i & 63;
        sW[swz(k, j)] = Wl[i];
        sW[swz(k + 64, j)] = Wr[i];
    }

    const int lane = tid & 15;
    const int grp = tid >> 4;
#pragma unroll
    for (int q = 0; q < 4; ++q) {
        int nl = grp * 4 + q;
        int n = n0 + nl;
        float4 am = make_float4(0.f, 0.f, 0.f, 0.f);
        float4 ax = am;
        if (n < N) {
            ushort4 mv = *(const ushort4*)(mh + (size_t)n * 64 + lane * 4);
            am = make_float4(bf2f(mv.x), bf2f(mv.y), bf2f(mv.z), bf2f(mv.w));
            ax = x4[(size_t)n * 16 + lane];
        }
        int f0 = lane * 4;
        sA[swz(f0 + 0, nl)] = am.x;
        sA[swz(f0 + 1, nl)] = am.y;
        sA[swz(f0 + 2, nl)] = am.z;
        sA[swz(f0 + 3, nl)] = am.w;
        sA[swz(f0 + 64, nl)] = ax.x;
        sA[swz(f0 + 65, nl)] = ax.y;
        sA[swz(f0 + 66, nl)] = ax.z;
        sA[swz(f0 + 67, nl)] = ax.w;
    }
    __syncthreads();

    const int jbase = (tid & 15) * 4;
    const int nb = ((tid >> 4) & 3) * 4 + (tid >> 6) * 16;
    float acc[4][4] = {};
#pragma unroll 4
    for (int k = 0; k < 128; ++k) {
        const int rot = (k << 2) & 63;
        float4 a = *(const float4*)(sA + (k << 6) + ((nb + rot) & 63));
        float4 w = *(const float4*)(sW + (k << 6) + ((jbase + rot) & 63));
        acc[0][0] += a.x * w.x; acc[0][1] += a.x * w.y; acc[0][2] += a.x * w.z; acc[0][3] += a.x * w.w;
        acc[1][0] += a.y * w.x; acc[1][1] += a.y * w.y; acc[1][2] += a.y * w.z; acc[1][3] += a.y * w.w;
        acc[2][0] += a.z * w.x; acc[2][1] += a.z * w.y; acc[2][2] += a.z * w.z; acc[2][3] += a.z * w.w;
        acc[3][0] += a.w * w.x; acc[3][1] += a.w * w.y; acc[3][2] += a.w * w.z; acc[3][3] += a.w * w.w;
    }

    float4 blv = *(const float4*)(bl + jbase);
    float psum[4] = {0.f, 0.f, 0.f, 0.f};
    float psq[4] = {0.f, 0.f, 0.f, 0.f};
#pragma unroll
    for (int q = 0; q < 4; ++q) {
        float h0 = acc[q][0] + blv.x;
        float h1 = acc[q][1] + blv.y;
        float h2 = acc[q][2] + blv.z;
        float h3 = acc[q][3] + blv.w;
        float ss = h0 * h0 + h1 * h1 + h2 * h2 + h3 * h3;
        ss += __shfl_xor(ss, 1);
        ss += __shfl_xor(ss, 2);
        ss += __shfl_xor(ss, 4);
        ss += __shfl_xor(ss, 8);
        float sc = 1.0f / fmaxf(sqrtf(ss), 1e-12f);
        float r0 = fmaxf(h0 * sc, 0.f);
        float r1 = fmaxf(h1 * sc, 0.f);
        float r2 = fmaxf(h2 * sc, 0.f);
        float r3 = fmaxf(h3 * sc, 0.f);
        unsigned short b0 = f2bf(r0), b1 = f2bf(r1), b2 = f2bf(r2), b3 = f2bf(r3);
        float e0 = bf2f(b0), e1 = bf2f(b1), e2 = bf2f(b2), e3 = bf2f(b3);
        int n = n0 + nb + q;
        if (n < N) {
            *(ushort4*)(mh + (size_t)n * 64 + jbase) = make_ushort4(b0, b1, b2, b3);
            psum[0] += e0; psum[1] += e1; psum[2] += e2; psum[3] += e3;
            psq[0] += e0 * e0; psq[1] += e1 * e1; psq[2] += e2 * e2; psq[3] += e3 * e3;
        }
    }

#pragma unroll
    for (int p = 0; p < 4; ++p) {
        psum[p] += __shfl_xor(psum[p], 16);
        psum[p] += __shfl_xor(psum[p], 32);
        psq[p] += __shfl_xor(psq[p], 16);
        psq[p] += __shfl_xor(psq[p], 32);
    }
    const int wid = tid >> 6;
    if ((tid & 63) < 16) {
        const int l = tid & 15;
#pragma unroll
        for (int p = 0; p < 4; ++p) {
            sRed[wid][l * 4 + p] = psum[p];
            sRed[wid][64 + l * 4 + p] = psq[p];
        }
    }
    __syncthreads();
    if (tid < 128) {
        float v = sRed[0][tid] + sRed[1][tid] + sRed[2][tid] + sRed[3][tid];
        pstats[(size_t)blockIdx.x * 128 + tid] = v;
    }
}

// ---------------------------------------------- reduce per-block BN partials
__global__ __launch_bounds__(64) void k_stats(const float* __restrict__ pstats,
                                              float* __restrict__ stats, int nblk) {
    int col = blockIdx.x;
    int l = threadIdx.x;
    float s = 0.f;
    for (int r = l; r < nblk; r += 64) s += pstats[(size_t)r * 128 + col];
    s += __shfl_xor(s, 1);
    s += __shfl_xor(s, 2);
    s += __shfl_xor(s, 4);
    s += __shfl_xor(s, 8);
    s += __shfl_xor(s, 16);
    s += __shfl_xor(s, 32);
    if (l == 0) stats[col] = s;
}

// ---------------------------------------------------------------- BN-fold + FC
__global__ __launch_bounds__(256) void k_out(
        const unsigned short* __restrict__ h, const float* __restrict__ stats,
        const float* __restrict__ gamma, const float* __restrict__ beta,
        const float* __restrict__ Wfc, const float* __restrict__ bfc,
        float* __restrict__ out, int N) {
    __shared__ float sWm[64 * 16];
    __shared__ float sShift[64];
    __shared__ float sBase[16];
    const int tid = threadIdx.x;
    const float invN = 1.0f / (float)N;
    if (tid < 64) {
        float mu = stats[tid] * invN;
        float var = stats[64 + tid] * invN - mu * mu;
        float sc = gamma[tid] / sqrtf(var + 1e-5f);
        sShift[tid] = beta[tid] - mu * sc;
#pragma unroll
        for (int c = 0; c < 16; ++c) sWm[tid * 16 + c] = Wfc[c * 64 + tid] * sc;
    }
    __syncthreads();
    if (tid < 16) {
        float b = bfc[tid];
#pragma unroll
        for (int j = 0; j < 64; ++j) b += sShift[j] * Wfc[tid * 64 + j];
        sBase[tid] = b;
    }
    __syncthreads();
    int g = blockIdx.x * 256 + tid;
    int n = g >> 4;
    int c = g & 15;
    if (n >= N) return;
    const ushort4* h4 = (const ushort4*)(h + (size_t)n * 64);
    float acc = sBase[c];
#pragma unroll
    for (int jq = 0; jq < 16; ++jq) {
        ushort4 v = h4[jq];
        acc += bf2f(v.x) * sWm[(jq * 4 + 0) * 16 + c];
        acc += bf2f(v.y) * sWm[(jq * 4 + 1) * 16 + c];
        acc += bf2f(v.z) * sWm[(jq * 4 + 2) * 16 + c];
        acc += bf2f(v.w) * sWm[(jq * 4 + 3) * 16 + c];
    }
    out[(size_t)n * 16 + c] = acc;
}

extern "C" void kernel_launch(void* const* d_in, const int* in_sizes, int n_in,
                              void* d_out, int out_size, void* d_ws, size_t ws_size,
                              hipStream_t stream) {
    const int* eidx = (const int*)d_in[0];
    const float* x = (const float*)d_in[1];
    const float* Wl = (const float*)d_in[2];
    const float* bl = (const float*)d_in[3];
    const float* Wr = (const float*)d_in[4];
    const float* gamma = (const float*)d_in[5];
    const float* beta = (const float*)d_in[6];
    const float* Wfc = (const float*)d_in[7];
    const float* bfc = (const float*)d_in[8];
    float* out = (float*)d_out;

    const int E = in_sizes[0] / 2;
    const int N = in_sizes[1] / 64;
    const int fblocks = (N + 63) / 64;
    const int sblocks = (N + 1023) / 1024;   // scan level-1 blocks (<=256)

    int* degcur = (int*)d_ws;                                  // N (zeroed)
    int* rowptr = degcur + N;                                  // N+1
    int* colv = rowptr + (N + 1);                              // E
    unsigned short* mh = (unsigned short*)(colv + E);          // N*64 bf16
    float* pstats = (float*)(mh + (size_t)N * 64);             // fblocks*128
    float* stats = pstats + (size_t)fblocks * 128;             // 128
    int* bsum = (int*)(stats + 128);                           // 256
    unsigned short* xbf = (unsigned short*)(bsum + 256);       // N*64 bf16 (optional)

    size_t need_bf = (size_t)((char*)(xbf + (size_t)N * 64) - (char*)d_ws);
    const bool use_bf16_x = (ws_size >= need_bf);

    hipMemsetAsync(d_ws, 0, (size_t)N * 4, stream);

    int eblocks = (E + 255) / 256;
    k_hist<<<eblocks, 256, 0, stream>>>(eidx, degcur, E);
    k_scan1<<<sblocks, 256, 0, stream>>>(degcur, rowptr, bsum, N);
    k_scan2<<<1, 256, 0, stream>>>(bsum, sblocks);
    k_scan3<<<sblocks, 256, 0, stream>>>(rowptr, bsum, degcur, N, E);
    k_fill<<<eblocks, 256, 0, stream>>>(eidx, degcur, colv, E);

    int gblocks = (int)(((size_t)N * 16 + 255) / 256);
    if (use_bf16_x) {
        int cblocks = (int)(((size_t)N * 16 + 255) / 256);
        k_xcast<<<cblocks, 256, 0, stream>>>((const float4*)x, (ushort4*)xbf, N * 16);
        k_gather_bf<<<gblocks, 256, 0, stream>>>((const ushort4*)xbf, rowptr, colv,
                                                 (ushort4*)mh, N);
    } else {
        k_gather_f32<<<gblocks, 256, 0, stream>>>((const float4*)x, rowptr, colv,
                                                  (ushort4*)mh, N);
    }

    k_fused<<<fblocks, 256, 0, stream>>>((const float4*)x, Wl, bl, Wr,
                                         mh, pstats, N);

    k_stats<<<128, 64, 0, stream>>>(pstats, stats, fblocks);

    int oblocks = (int)(((size_t)N * 16 + 255) / 256);
    k_out<<<oblocks, 256, 0, stream>>>(mh, stats, gamma, beta, Wfc, bfc, out, N);
}

// Round 6
// 281.724 us; speedup vs baseline: 6.3966x; 1.2576x over previous
//
#include <hip/hip_runtime.h>
#include <hip/hip_bf16.h>

// SAGEConv(mean) via CSR (atomic-free fill using hist-rank trick) + bf16 gather
// + fused GEMM/L2norm/ReLU/BN-partials + stats-reduce + BN-fold FC.
// N=100000, E=1200000, F=H=64, C=16.
//
// ws layout (4B words):
//   [deg: N][rowptr: N+1][colv: E][rank: E][mh: N*32 (bf16 mean->h)]
//   [pstats: fblocks*128][stats: 128][bsum: 256][xbf: N*32 (bf16 x, optional)]
// Only deg needs zeroing.
// Lessons: R4 — same-address f32 atomics cross-XCD = ~600us. R5 — per-edge
// cursor atomics in fill = 99us and 64B/atomic coherence traffic; rank trick
// (reuse hist's atomic return value) makes fill atomic-free.

__device__ __forceinline__ int swz(int row, int col) {
    return (row << 6) + ((col + ((row << 2) & 63)) & 63);
}

__device__ __forceinline__ unsigned short f2bf(float f) {
    unsigned int u = __builtin_bit_cast(unsigned int, f);
    u += 0x7FFFu + ((u >> 16) & 1u);
    return (unsigned short)(u >> 16);
}
__device__ __forceinline__ float bf2f(unsigned short s) {
    return __builtin_bit_cast(float, ((unsigned int)s) << 16);
}

// ------------------------------------- degree hist + per-edge rank (one atomic)
__global__ __launch_bounds__(256) void k_histrank(const int* __restrict__ eidx,
                                                  int* __restrict__ deg,
                                                  int* __restrict__ rank, int E) {
    int t = blockIdx.x * 256 + threadIdx.x;
    if (t < E) rank[t] = atomicAdd(&deg[eidx[E + t]], 1);
}

// ------------------------------------------- scan level 1: per-block local scan
__global__ __launch_bounds__(256) void k_scan1(const int* __restrict__ deg,
                                               int* __restrict__ rowptr,
                                               int* __restrict__ bsum, int N) {
    __shared__ int swave[4];
    const int tid = threadIdx.x;
    const int base = blockIdx.x * 1024 + tid * 4;
    int v0 = (base + 0 < N) ? deg[base + 0] : 0;
    int v1 = (base + 1 < N) ? deg[base + 1] : 0;
    int v2 = (base + 2 < N) ? deg[base + 2] : 0;
    int v3 = (base + 3 < N) ? deg[base + 3] : 0;
    int tsum = v0 + v1 + v2 + v3;
    const int lane = tid & 63, wid = tid >> 6;
    int s = tsum;
#pragma unroll
    for (int off = 1; off < 64; off <<= 1) {
        int t = __shfl_up(s, off);
        if (lane >= off) s += t;
    }
    if (lane == 63) swave[wid] = s;
    __syncthreads();
    if (tid == 0) {
        int a = 0;
#pragma unroll
        for (int w = 0; w < 4; ++w) { int t = swave[w]; swave[w] = a; a += t; }
    }
    __syncthreads();
    int run = s - tsum + swave[wid];
    if (base + 0 < N) rowptr[base + 0] = run; run += v0;
    if (base + 1 < N) rowptr[base + 1] = run; run += v1;
    if (base + 2 < N) rowptr[base + 2] = run; run += v2;
    if (base + 3 < N) rowptr[base + 3] = run;
    if (tid == 255) bsum[blockIdx.x] = swave[3] + s;
}

// ------------------------------------------- scan level 2: scan the block sums
__global__ __launch_bounds__(256) void k_scan2(int* __restrict__ bsum, int nblk) {
    __shared__ int s[256];
    int tid = threadIdx.x;
    int v = (tid < nblk) ? bsum[tid] : 0;
    s[tid] = v;
    __syncthreads();
    for (int off = 1; off < 256; off <<= 1) {
        int t = (tid >= off) ? s[tid - off] : 0;
        __syncthreads();
        s[tid] += t;
        __syncthreads();
    }
    if (tid < nblk) bsum[tid] = s[tid] - v;
}

// ------------------------------------------- scan level 3: add block offsets
__global__ __launch_bounds__(256) void k_scan3(int* __restrict__ rowptr,
                                               const int* __restrict__ bsum,
                                               int N, int E) {
    const int tid = threadIdx.x;
    const int base = blockIdx.x * 1024 + tid * 4;
    const int off = bsum[blockIdx.x];
#pragma unroll
    for (int p = 0; p < 4; ++p) {
        int i = base + p;
        if (i < N) rowptr[i] += off;
    }
    if (blockIdx.x == 0 && tid == 0) rowptr[N] = E;
}

// --------------------------------------------- CSR fill, atomic-free via rank
__global__ __launch_bounds__(256) void k_fill(const int* __restrict__ eidx,
                                              const int* __restrict__ rowptr,
                                              const int* __restrict__ rank,
                                              int* __restrict__ colv, int E) {
    int t = blockIdx.x * 256 + threadIdx.x;
    if (t < E) {
        int d = eidx[E + t];
        colv[rowptr[d] + rank[t]] = eidx[t];
    }
}

// ---------------------------------------------------------------- x -> bf16
__global__ __launch_bounds__(256) void k_xcast(const float4* __restrict__ x4,
                                               ushort4* __restrict__ xbf, int n4) {
    int t = blockIdx.x * 256 + threadIdx.x;
    if (t < n4) {
        float4 v = x4[t];
        xbf[t] = make_ushort4(f2bf(v.x), f2bf(v.y), f2bf(v.z), f2bf(v.w));
    }
}

// ------------------------- gather-mean (bf16 x): 16 lanes/node, full occupancy
__global__ __launch_bounds__(256) void k_gather_bf(
        const ushort4* __restrict__ xbf, const int* __restrict__ rowptr,
        const int* __restrict__ colv, ushort4* __restrict__ mh, int N) {
    int t = blockIdx.x * 256 + threadIdx.x;
    int n = t >> 4;
    int l = t & 15;
    if (n >= N) return;
    int b = rowptr[n], e = rowptr[n + 1];
    float ax = 0.f, ay = 0.f, az = 0.f, aw = 0.f;
    int p = b;
    for (; p + 4 <= e; p += 4) {
        int s0 = colv[p], s1 = colv[p + 1], s2 = colv[p + 2], s3 = colv[p + 3];
        ushort4 v0 = xbf[(size_t)s0 * 16 + l];
        ushort4 v1 = xbf[(size_t)s1 * 16 + l];
        ushort4 v2 = xbf[(size_t)s2 * 16 + l];
        ushort4 v3 = xbf[(size_t)s3 * 16 + l];
        ax += (bf2f(v0.x) + bf2f(v1.x)) + (bf2f(v2.x) + bf2f(v3.x));
        ay += (bf2f(v0.y) + bf2f(v1.y)) + (bf2f(v2.y) + bf2f(v3.y));
        az += (bf2f(v0.z) + bf2f(v1.z)) + (bf2f(v2.z) + bf2f(v3.z));
        aw += (bf2f(v0.w) + bf2f(v1.w)) + (bf2f(v2.w) + bf2f(v3.w));
    }
    for (; p < e; ++p) {
        int s0 = colv[p];
        ushort4 v0 = xbf[(size_t)s0 * 16 + l];
        ax += bf2f(v0.x); ay += bf2f(v0.y); az += bf2f(v0.z); aw += bf2f(v0.w);
    }
    float inv = 1.0f / fmaxf((float)(e - b), 1.0f);
    mh[(size_t)n * 16 + l] = make_ushort4(f2bf(ax * inv), f2bf(ay * inv),
                                          f2bf(az * inv), f2bf(aw * inv));
}

// ------------------------- gather-mean (f32 x fallback, if ws too small)
__global__ __launch_bounds__(256) void k_gather_f32(
        const float4* __restrict__ x4, const int* __restrict__ rowptr,
        const int* __restrict__ colv, ushort4* __restrict__ mh, int N) {
    int t = blockIdx.x * 256 + threadIdx.x;
    int n = t >> 4;
    int l = t & 15;
    if (n >= N) return;
    int b = rowptr[n], e = rowptr[n + 1];
    float ax = 0.f, ay = 0.f, az = 0.f, aw = 0.f;
    int p = b;
    for (; p + 4 <= e; p += 4) {
        int s0 = colv[p], s1 = colv[p + 1], s2 = colv[p + 2], s3 = colv[p + 3];
        float4 v0 = x4[(size_t)s0 * 16 + l];
        float4 v1 = x4[(size_t)s1 * 16 + l];
        float4 v2 = x4[(size_t)s2 * 16 + l];
        float4 v3 = x4[(size_t)s3 * 16 + l];
        ax += (v0.x + v1.x) + (v2.x + v3.x);
        ay += (v0.y + v1.y) + (v2.y + v3.y);
        az += (v0.z + v1.z) + (v2.z + v3.z);
        aw += (v0.w + v1.w) + (v2.w + v3.w);
    }
    for (; p < e; ++p) {
        int s0 = colv[p];
        float4 v0 = x4[(size_t)s0 * 16 + l];
        ax += v0.x; ay += v0.y; az += v0.z; aw += v0.w;
    }
    float inv = 1.0f / fmaxf((float)(e - b), 1.0f);
    mh[(size_t)n * 16 + l] = make_ushort4(f2bf(ax * inv), f2bf(ay * inv),
                                          f2bf(az * inv), f2bf(aw * inv));
}

// --------- fused: [mean|x]@[Wl;Wr]^T + bl, L2norm, ReLU, BN partials; h over mh
__global__ __launch_bounds__(256) void k_fused(
        const float4* __restrict__ x4,
        const float* __restrict__ Wl, const float* __restrict__ bl,
        const float* __restrict__ Wr,
        unsigned short* __restrict__ mh,
        float* __restrict__ pstats, int N) {
    __shared__ float sW[128 * 64];
    __shared__ float sA[128 * 64];
    __shared__ float sRed[4][128];

    const int tid = threadIdx.x;
    const int n0 = blockIdx.x * 64;

    for (int i = tid; i < 64 * 64; i += 256) {
        int j = i >> 6, k = i & 63;
        sW[swz(k, j)] = Wl[i];
        sW[swz(k + 64, j)] = Wr[i];
    }

    const int lane = tid & 15;
    const int grp = tid >> 4;
#pragma unroll
    for (int q = 0; q < 4; ++q) {
        int nl = grp * 4 + q;
        int n = n0 + nl;
        float4 am = make_float4(0.f, 0.f, 0.f, 0.f);
        float4 ax = am;
        if (n < N) {
            ushort4 mv = *(const ushort4*)(mh + (size_t)n * 64 + lane * 4);
            am = make_float4(bf2f(mv.x), bf2f(mv.y), bf2f(mv.z), bf2f(mv.w));
            ax = x4[(size_t)n * 16 + lane];
        }
        int f0 = lane * 4;
        sA[swz(f0 + 0, nl)] = am.x;
        sA[swz(f0 + 1, nl)] = am.y;
        sA[swz(f0 + 2, nl)] = am.z;
        sA[swz(f0 + 3, nl)] = am.w;
        sA[swz(f0 + 64, nl)] = ax.x;
        sA[swz(f0 + 65, nl)] = ax.y;
        sA[swz(f0 + 66, nl)] = ax.z;
        sA[swz(f0 + 67, nl)] = ax.w;
    }
    __syncthreads();

    const int jbase = (tid & 15) * 4;
    const int nb = ((tid >> 4) & 3) * 4 + (tid >> 6) * 16;
    float acc[4][4] = {};
#pragma unroll 4
    for (int k = 0; k < 128; ++k) {
        const int rot = (k << 2) & 63;
        float4 a = *(const float4*)(sA + (k << 6) + ((nb + rot) & 63));
        float4 w = *(const float4*)(sW + (k << 6) + ((jbase + rot) & 63));
        acc[0][0] += a.x * w.x; acc[0][1] += a.x * w.y; acc[0][2] += a.x * w.z; acc[0][3] += a.x * w.w;
        acc[1][0] += a.y * w.x; acc[1][1] += a.y * w.y; acc[1][2] += a.y * w.z; acc[1][3] += a.y * w.w;
        acc[2][0] += a.z * w.x; acc[2][1] += a.z * w.y; acc[2][2] += a.z * w.z; acc[2][3] += a.z * w.w;
        acc[3][0] += a.w * w.x; acc[3][1] += a.w * w.y; acc[3][2] += a.w * w.z; acc[3][3] += a.w * w.w;
    }

    float4 blv = *(const float4*)(bl + jbase);
    float psum[4] = {0.f, 0.f, 0.f, 0.f};
    float psq[4] = {0.f, 0.f, 0.f, 0.f};
#pragma unroll
    for (int q = 0; q < 4; ++q) {
        float h0 = acc[q][0] + blv.x;
        float h1 = acc[q][1] + blv.y;
        float h2 = acc[q][2] + blv.z;
        float h3 = acc[q][3] + blv.w;
        float ss = h0 * h0 + h1 * h1 + h2 * h2 + h3 * h3;
        ss += __shfl_xor(ss, 1);
        ss += __shfl_xor(ss, 2);
        ss += __shfl_xor(ss, 4);
        ss += __shfl_xor(ss, 8);
        float sc = 1.0f / fmaxf(sqrtf(ss), 1e-12f);
        float r0 = fmaxf(h0 * sc, 0.f);
        float r1 = fmaxf(h1 * sc, 0.f);
        float r2 = fmaxf(h2 * sc, 0.f);
        float r3 = fmaxf(h3 * sc, 0.f);
        unsigned short b0 = f2bf(r0), b1 = f2bf(r1), b2 = f2bf(r2), b3 = f2bf(r3);
        float e0 = bf2f(b0), e1 = bf2f(b1), e2 = bf2f(b2), e3 = bf2f(b3);
        int n = n0 + nb + q;
        if (n < N) {
            *(ushort4*)(mh + (size_t)n * 64 + jbase) = make_ushort4(b0, b1, b2, b3);
            psum[0] += e0; psum[1] += e1; psum[2] += e2; psum[3] += e3;
            psq[0] += e0 * e0; psq[1] += e1 * e1; psq[2] += e2 * e2; psq[3] += e3 * e3;
        }
    }

#pragma unroll
    for (int p = 0; p < 4; ++p) {
        psum[p] += __shfl_xor(psum[p], 16);
        psum[p] += __shfl_xor(psum[p], 32);
        psq[p] += __shfl_xor(psq[p], 16);
        psq[p] += __shfl_xor(psq[p], 32);
    }
    const int wid = tid >> 6;
    if ((tid & 63) < 16) {
        const int l = tid & 15;
#pragma unroll
        for (int p = 0; p < 4; ++p) {
            sRed[wid][l * 4 + p] = psum[p];
            sRed[wid][64 + l * 4 + p] = psq[p];
        }
    }
    __syncthreads();
    if (tid < 128) {
        float v = sRed[0][tid] + sRed[1][tid] + sRed[2][tid] + sRed[3][tid];
        pstats[(size_t)blockIdx.x * 128 + tid] = v;
    }
}

// ---------------------------------------------- reduce per-block BN partials
__global__ __launch_bounds__(64) void k_stats(const float* __restrict__ pstats,
                                              float* __restrict__ stats, int nblk) {
    int col = blockIdx.x;
    int l = threadIdx.x;
    float s = 0.f;
    for (int r = l; r < nblk; r += 64) s += pstats[(size_t)r * 128 + col];
    s += __shfl_xor(s, 1);
    s += __shfl_xor(s, 2);
    s += __shfl_xor(s, 4);
    s += __shfl_xor(s, 8);
    s += __shfl_xor(s, 16);
    s += __shfl_xor(s, 32);
    if (l == 0) stats[col] = s;
}

// ---------------------------------------------------------------- BN-fold + FC
__global__ __launch_bounds__(256) void k_out(
        const unsigned short* __restrict__ h, const float* __restrict__ stats,
        const float* __restrict__ gamma, const float* __restrict__ beta,
        const float* __restrict__ Wfc, const float* __restrict__ bfc,
        float* __restrict__ out, int N) {
    __shared__ float sWm[64 * 16];
    __shared__ float sShift[64];
    __shared__ float sBase[16];
    const int tid = threadIdx.x;
    const float invN = 1.0f / (float)N;
    if (tid < 64) {
        float mu = stats[tid] * invN;
        float var = stats[64 + tid] * invN - mu * mu;
        float sc = gamma[tid] / sqrtf(var + 1e-5f);
        sShift[tid] = beta[tid] - mu * sc;
#pragma unroll
        for (int c = 0; c < 16; ++c) sWm[tid * 16 + c] = Wfc[c * 64 + tid] * sc;
    }
    __syncthreads();
    if (tid < 16) {
        float b = bfc[tid];
#pragma unroll
        for (int j = 0; j < 64; ++j) b += sShift[j] * Wfc[tid * 64 + j];
        sBase[tid] = b;
    }
    __syncthreads();
    int g = blockIdx.x * 256 + tid;
    int n = g >> 4;
    int c = g & 15;
    if (n >= N) return;
    const ushort4* h4 = (const ushort4*)(h + (size_t)n * 64);
    float acc = sBase[c];
#pragma unroll
    for (int jq = 0; jq < 16; ++jq) {
        ushort4 v = h4[jq];
        acc += bf2f(v.x) * sWm[(jq * 4 + 0) * 16 + c];
        acc += bf2f(v.y) * sWm[(jq * 4 + 1) * 16 + c];
        acc += bf2f(v.z) * sWm[(jq * 4 + 2) * 16 + c];
        acc += bf2f(v.w) * sWm[(jq * 4 + 3) * 16 + c];
    }
    out[(size_t)n * 16 + c] = acc;
}

extern "C" void kernel_launch(void* const* d_in, const int* in_sizes, int n_in,
                              void* d_out, int out_size, void* d_ws, size_t ws_size,
                              hipStream_t stream) {
    const int* eidx = (const int*)d_in[0];
    const float* x = (const float*)d_in[1];
    const float* Wl = (const float*)d_in[2];
    const float* bl = (const float*)d_in[3];
    const float* Wr = (const float*)d_in[4];
    const float* gamma = (const float*)d_in[5];
    const float* beta = (const float*)d_in[6];
    const float* Wfc = (const float*)d_in[7];
    const float* bfc = (const float*)d_in[8];
    float* out = (float*)d_out;

    const int E = in_sizes[0] / 2;
    const int N = in_sizes[1] / 64;
    const int fblocks = (N + 63) / 64;
    const int sblocks = (N + 1023) / 1024;

    int* deg = (int*)d_ws;                                     // N (zeroed)
    int* rowptr = deg + N;                                     // N+1
    int* colv = rowptr + (N + 1);                              // E
    int* rank = colv + E;                                      // E
    unsigned short* mh = (unsigned short*)(rank + E);          // N*64 bf16
    float* pstats = (float*)(mh + (size_t)N * 64);             // fblocks*128
    float* stats = pstats + (size_t)fblocks * 128;             // 128
    int* bsum = (int*)(stats + 128);                           // 256
    unsigned short* xbf = (unsigned short*)(bsum + 256);       // N*64 bf16 (optional)

    size_t need_bf = (size_t)((char*)(xbf + (size_t)N * 64) - (char*)d_ws);
    const bool use_bf16_x = (ws_size >= need_bf);

    hipMemsetAsync(d_ws, 0, (size_t)N * 4, stream);

    int eblocks = (E + 255) / 256;
    k_histrank<<<eblocks, 256, 0, stream>>>(eidx, deg, rank, E);
    k_scan1<<<sblocks, 256, 0, stream>>>(deg, rowptr, bsum, N);
    k_scan2<<<1, 256, 0, stream>>>(bsum, sblocks);
    k_scan3<<<sblocks, 256, 0, stream>>>(rowptr, bsum, N, E);
    k_fill<<<eblocks, 256, 0, stream>>>(eidx, rowptr, rank, colv, E);

    int gblocks = (int)(((size_t)N * 16 + 255) / 256);
    if (use_bf16_x) {
        k_xcast<<<gblocks, 256, 0, stream>>>((const float4*)x, (ushort4*)xbf, N * 16);
        k_gather_bf<<<gblocks, 256, 0, stream>>>((const ushort4*)xbf, rowptr, colv,
                                                 (ushort4*)mh, N);
    } else {
        k_gather_f32<<<gblocks, 256, 0, stream>>>((const float4*)x, rowptr, colv,
                                                  (ushort4*)mh, N);
    }

    k_fused<<<fblocks, 256, 0, stream>>>((const float4*)x, Wl, bl, Wr,
                                         mh, pstats, N);

    k_stats<<<128, 64, 0, stream>>>(pstats, stats, fblocks);

    int oblocks = (int)(((size_t)N * 16 + 255) / 256);
    k_out<<<oblocks, 256, 0, stream>>>(mh, stats, gamma, beta, Wfc, bfc, out, N);
}

// Round 7
// 266.483 us; speedup vs baseline: 6.7625x; 1.0572x over previous
//
#include <hip/hip_runtime.h>
#include <hip/hip_bf16.h>

// SAGEConv(mean) via CSR (rank-trick atomic-free fill) + bf16 gather +
// MFMA-based fused [mean|x]@[Wl;Wr]^T + L2norm + ReLU + BN-partials +
// stats-reduce + BN-fold FC.  N=100000, E=1200000, F=H=64, C=16.
//
// ws layout (4B words):
//   [deg: N][rowptr: N+1][colv: E][rank: E][mh: N*32 (bf16 mean->h)]
//   [pstats: fblocks*128][stats: 128][bsum: 256][xbf: N*32 (bf16 x, optional)]
// Lessons: R4 — same-address f32 atomics cross-XCD = ~600us. R5 — per-edge
// cursor atomics = 99us (64B coherence line per atomic). R6 — fp32 VALU GEMM
// with 66KB LDS = 58us @ 2 blocks/CU; replaced by per-wave MFMA tiles with
// zero GEMM LDS (A direct from bf16 mh / converted x, B frags in registers).

typedef __attribute__((ext_vector_type(8))) short short8;   // 8 bf16
typedef __attribute__((ext_vector_type(4))) float f32x4;

__device__ __forceinline__ unsigned short f2bf(float f) {
    unsigned int u = __builtin_bit_cast(unsigned int, f);
    u += 0x7FFFu + ((u >> 16) & 1u);
    return (unsigned short)(u >> 16);
}
__device__ __forceinline__ float bf2f(unsigned short s) {
    return __builtin_bit_cast(float, ((unsigned int)s) << 16);
}

// ------------------------------------- degree hist + per-edge rank (one atomic)
__global__ __launch_bounds__(256) void k_histrank(const int* __restrict__ eidx,
                                                  int* __restrict__ deg,
                                                  int* __restrict__ rank, int E) {
    int t = blockIdx.x * 256 + threadIdx.x;
    if (t < E) rank[t] = atomicAdd(&deg[eidx[E + t]], 1);
}

// ------------------------------------------- scan level 1: per-block local scan
__global__ __launch_bounds__(256) void k_scan1(const int* __restrict__ deg,
                                               int* __restrict__ rowptr,
                                               int* __restrict__ bsum, int N) {
    __shared__ int swave[4];
    const int tid = threadIdx.x;
    const int base = blockIdx.x * 1024 + tid * 4;
    int v0 = (base + 0 < N) ? deg[base + 0] : 0;
    int v1 = (base + 1 < N) ? deg[base + 1] : 0;
    int v2 = (base + 2 < N) ? deg[base + 2] : 0;
    int v3 = (base + 3 < N) ? deg[base + 3] : 0;
    int tsum = v0 + v1 + v2 + v3;
    const int lane = tid & 63, wid = tid >> 6;
    int s = tsum;
#pragma unroll
    for (int off = 1; off < 64; off <<= 1) {
        int t = __shfl_up(s, off);
        if (lane >= off) s += t;
    }
    if (lane == 63) swave[wid] = s;
    __syncthreads();
    if (tid == 0) {
        int a = 0;
#pragma unroll
        for (int w = 0; w < 4; ++w) { int t = swave[w]; swave[w] = a; a += t; }
    }
    __syncthreads();
    int run = s - tsum + swave[wid];
    if (base + 0 < N) rowptr[base + 0] = run; run += v0;
    if (base + 1 < N) rowptr[base + 1] = run; run += v1;
    if (base + 2 < N) rowptr[base + 2] = run; run += v2;
    if (base + 3 < N) rowptr[base + 3] = run;
    if (tid == 255) bsum[blockIdx.x] = swave[3] + s;
}

// ------------------------------------------- scan level 2: scan the block sums
__global__ __launch_bounds__(256) void k_scan2(int* __restrict__ bsum, int nblk) {
    __shared__ int s[256];
    int tid = threadIdx.x;
    int v = (tid < nblk) ? bsum[tid] : 0;
    s[tid] = v;
    __syncthreads();
    for (int off = 1; off < 256; off <<= 1) {
        int t = (tid >= off) ? s[tid - off] : 0;
        __syncthreads();
        s[tid] += t;
        __syncthreads();
    }
    if (tid < nblk) bsum[tid] = s[tid] - v;
}

// ------------------------------------------- scan level 3: add block offsets
__global__ __launch_bounds__(256) void k_scan3(int* __restrict__ rowptr,
                                               const int* __restrict__ bsum,
                                               int N, int E) {
    const int tid = threadIdx.x;
    const int base = blockIdx.x * 1024 + tid * 4;
    const int off = bsum[blockIdx.x];
#pragma unroll
    for (int p = 0; p < 4; ++p) {
        int i = base + p;
        if (i < N) rowptr[i] += off;
    }
    if (blockIdx.x == 0 && tid == 0) rowptr[N] = E;
}

// --------------------------------------------- CSR fill, atomic-free via rank
__global__ __launch_bounds__(256) void k_fill(const int* __restrict__ eidx,
                                              const int* __restrict__ rowptr,
                                              const int* __restrict__ rank,
                                              int* __restrict__ colv, int E) {
    int t = blockIdx.x * 256 + threadIdx.x;
    if (t < E) {
        int d = eidx[E + t];
        colv[rowptr[d] + rank[t]] = eidx[t];
    }
}

// ---------------------------------------------------------------- x -> bf16
__global__ __launch_bounds__(256) void k_xcast(const float4* __restrict__ x4,
                                               ushort4* __restrict__ xbf, int n4) {
    int t = blockIdx.x * 256 + threadIdx.x;
    if (t < n4) {
        float4 v = x4[t];
        xbf[t] = make_ushort4(f2bf(v.x), f2bf(v.y), f2bf(v.z), f2bf(v.w));
    }
}

// ------------------------- gather-mean (bf16 x): 16 lanes/node, full occupancy
__global__ __launch_bounds__(256) void k_gather_bf(
        const ushort4* __restrict__ xbf, const int* __restrict__ rowptr,
        const int* __restrict__ colv, ushort4* __restrict__ mh, int N) {
    int t = blockIdx.x * 256 + threadIdx.x;
    int n = t >> 4;
    int l = t & 15;
    if (n >= N) return;
    int b = rowptr[n], e = rowptr[n + 1];
    float ax = 0.f, ay = 0.f, az = 0.f, aw = 0.f;
    int p = b;
    for (; p + 4 <= e; p += 4) {
        int s0 = colv[p], s1 = colv[p + 1], s2 = colv[p + 2], s3 = colv[p + 3];
        ushort4 v0 = xbf[(size_t)s0 * 16 + l];
        ushort4 v1 = xbf[(size_t)s1 * 16 + l];
        ushort4 v2 = xbf[(size_t)s2 * 16 + l];
        ushort4 v3 = xbf[(size_t)s3 * 16 + l];
        ax += (bf2f(v0.x) + bf2f(v1.x)) + (bf2f(v2.x) + bf2f(v3.x));
        ay += (bf2f(v0.y) + bf2f(v1.y)) + (bf2f(v2.y) + bf2f(v3.y));
        az += (bf2f(v0.z) + bf2f(v1.z)) + (bf2f(v2.z) + bf2f(v3.z));
        aw += (bf2f(v0.w) + bf2f(v1.w)) + (bf2f(v2.w) + bf2f(v3.w));
    }
    for (; p < e; ++p) {
        int s0 = colv[p];
        ushort4 v0 = xbf[(size_t)s0 * 16 + l];
        ax += bf2f(v0.x); ay += bf2f(v0.y); az += bf2f(v0.z); aw += bf2f(v0.w);
    }
    float inv = 1.0f / fmaxf((float)(e - b), 1.0f);
    mh[(size_t)n * 16 + l] = make_ushort4(f2bf(ax * inv), f2bf(ay * inv),
                                          f2bf(az * inv), f2bf(aw * inv));
}

// ------------------------- gather-mean (f32 x fallback, if ws too small)
__global__ __launch_bounds__(256) void k_gather_f32(
        const float4* __restrict__ x4, const int* __restrict__ rowptr,
        const int* __restrict__ colv, ushort4* __restrict__ mh, int N) {
    int t = blockIdx.x * 256 + threadIdx.x;
    int n = t >> 4;
    int l = t & 15;
    if (n >= N) return;
    int b = rowptr[n], e = rowptr[n + 1];
    float ax = 0.f, ay = 0.f, az = 0.f, aw = 0.f;
    int p = b;
    for (; p + 4 <= e; p += 4) {
        int s0 = colv[p], s1 = colv[p + 1], s2 = colv[p + 2], s3 = colv[p + 3];
        float4 v0 = x4[(size_t)s0 * 16 + l];
        float4 v1 = x4[(size_t)s1 * 16 + l];
        float4 v2 = x4[(size_t)s2 * 16 + l];
        float4 v3 = x4[(size_t)s3 * 16 + l];
        ax += (v0.x + v1.x) + (v2.x + v3.x);
        ay += (v0.y + v1.y) + (v2.y + v3.y);
        az += (v0.z + v1.z) + (v2.z + v3.z);
        aw += (v0.w + v1.w) + (v2.w + v3.w);
    }
    for (; p < e; ++p) {
        int s0 = colv[p];
        float4 v0 = x4[(size_t)s0 * 16 + l];
        ax += v0.x; ay += v0.y; az += v0.z; aw += v0.w;
    }
    float inv = 1.0f / fmaxf((float)(e - b), 1.0f);
    mh[(size_t)n * 16 + l] = make_ushort4(f2bf(ax * inv), f2bf(ay * inv),
                                          f2bf(az * inv), f2bf(aw * inv));
}

// --------- fused MFMA: [mean|x]@[Wl;Wr]^T + bl, L2norm, ReLU, BN partials.
// One wave = one 16-node tile. A: m=lane&15, k=quad*8+j (direct 16B loads).
// C/D: col=lane&15 (feature within f-tile), row=quad*4+reg (node within tile).
__global__ __launch_bounds__(256) void k_fused(
        const float* __restrict__ x,
        const float* __restrict__ Wl, const float* __restrict__ bl,
        const float* __restrict__ Wr,
        unsigned short* __restrict__ mh,   // in: bf16 mean; out: bf16 h
        float* __restrict__ pstats, int N) {
    __shared__ float sRed[4][128];

    const int tid = threadIdx.x;
    const int wid = tid >> 6;
    const int lane = tid & 63;
    const int l15 = lane & 15;
    const int quad = lane >> 4;
    const int tbase = blockIdx.x * 64 + wid * 16;

    // ---- B fragments: B[k=c*32+quad*8+j][n=f*16+l15] = Wcomb[n][k]
    // c=0,1 -> Wl rows; c=2,3 -> Wr rows. 16 frags x 8 bf16 in registers.
    short8 bfrag[4][4];
#pragma unroll
    for (int c = 0; c < 4; ++c) {
#pragma unroll
        for (int f = 0; f < 4; ++f) {
            const int n = f * 16 + l15;
            const float* wsrc = (c < 2)
                ? (Wl + (size_t)n * 64 + c * 32 + quad * 8)
                : (Wr + (size_t)n * 64 + (c - 2) * 32 + quad * 8);
            float4 w0 = *(const float4*)wsrc;
            float4 w1 = *(const float4*)(wsrc + 4);
            union { short8 v; unsigned short u[8]; } pk;
            pk.u[0] = f2bf(w0.x); pk.u[1] = f2bf(w0.y);
            pk.u[2] = f2bf(w0.z); pk.u[3] = f2bf(w0.w);
            pk.u[4] = f2bf(w1.x); pk.u[5] = f2bf(w1.y);
            pk.u[6] = f2bf(w1.z); pk.u[7] = f2bf(w1.w);
            bfrag[c][f] = pk.v;
        }
    }

    // ---- A fragments + MFMA
    const int mrow = tbase + l15;
    const int mld = (mrow < N) ? mrow : (N - 1);   // clamp: stay in-bounds
    f32x4 acc[4] = {{0.f, 0.f, 0.f, 0.f}, {0.f, 0.f, 0.f, 0.f},
                    {0.f, 0.f, 0.f, 0.f}, {0.f, 0.f, 0.f, 0.f}};
#pragma unroll
    for (int c = 0; c < 2; ++c) {    // mean half (already bf16)
        short8 a = *(const short8*)(mh + (size_t)mld * 64 + c * 32 + quad * 8);
#pragma unroll
        for (int f = 0; f < 4; ++f)
            acc[f] = __builtin_amdgcn_mfma_f32_16x16x32_bf16(a, bfrag[c][f], acc[f], 0, 0, 0);
    }
#pragma unroll
    for (int c = 2; c < 4; ++c) {    // root half (f32 x -> bf16 in-register)
        const float* xp = x + (size_t)mld * 64 + (c - 2) * 32 + quad * 8;
        float4 a0 = *(const float4*)xp;
        float4 a1 = *(const float4*)(xp + 4);
        union { short8 v; unsigned short u[8]; } pk;
        pk.u[0] = f2bf(a0.x); pk.u[1] = f2bf(a0.y);
        pk.u[2] = f2bf(a0.z); pk.u[3] = f2bf(a0.w);
        pk.u[4] = f2bf(a1.x); pk.u[5] = f2bf(a1.y);
        pk.u[6] = f2bf(a1.z); pk.u[7] = f2bf(a1.w);
#pragma unroll
        for (int f = 0; f < 4; ++f)
            acc[f] = __builtin_amdgcn_mfma_f32_16x16x32_bf16(pk.v, bfrag[c][f], acc[f], 0, 0, 0);
    }

    // ---- epilogue
    float blv[4];
#pragma unroll
    for (int f = 0; f < 4; ++f) blv[f] = bl[f * 16 + l15];

    float psum[4] = {0.f, 0.f, 0.f, 0.f};
    float psq[4] = {0.f, 0.f, 0.f, 0.f};
#pragma unroll
    for (int reg = 0; reg < 4; ++reg) {
        const int node = tbase + quad * 4 + reg;
        float hv[4];
        float ss = 0.f;
#pragma unroll
        for (int f = 0; f < 4; ++f) {
            hv[f] = acc[f][reg] + blv[f];
            ss += hv[f] * hv[f];
        }
        ss += __shfl_xor(ss, 1);
        ss += __shfl_xor(ss, 2);
        ss += __shfl_xor(ss, 4);
        ss += __shfl_xor(ss, 8);
        float sc = 1.0f / fmaxf(sqrtf(ss), 1e-12f);
        if (node < N) {
#pragma unroll
            for (int f = 0; f < 4; ++f) {
                float r = fmaxf(hv[f] * sc, 0.f);
                unsigned short rb = f2bf(r);
                float e = bf2f(rb);
                mh[(size_t)node * 64 + f * 16 + l15] = rb;
                psum[f] += e;
                psq[f] += e * e;
            }
        }
    }

    // reduce across quads (nodes) -> lanes 0..15 hold per-feature totals
#pragma unroll
    for (int f = 0; f < 4; ++f) {
        psum[f] += __shfl_xor(psum[f], 16);
        psum[f] += __shfl_xor(psum[f], 32);
        psq[f] += __shfl_xor(psq[f], 16);
        psq[f] += __shfl_xor(psq[f], 32);
    }
    if (lane < 16) {
#pragma unroll
        for (int f = 0; f < 4; ++f) {
            sRed[wid][f * 16 + l15] = psum[f];
            sRed[wid][64 + f * 16 + l15] = psq[f];
        }
    }
    __syncthreads();
    if (tid < 128) {
        float v = sRed[0][tid] + sRed[1][tid] + sRed[2][tid] + sRed[3][tid];
        pstats[(size_t)blockIdx.x * 128 + tid] = v;
    }
}

// ---------------------------------------------- reduce per-block BN partials
__global__ __launch_bounds__(64) void k_stats(const float* __restrict__ pstats,
                                              float* __restrict__ stats, int nblk) {
    int col = blockIdx.x;
    int l = threadIdx.x;
    float s = 0.f;
    for (int r = l; r < nblk; r += 64) s += pstats[(size_t)r * 128 + col];
    s += __shfl_xor(s, 1);
    s += __shfl_xor(s, 2);
    s += __shfl_xor(s, 4);
    s += __shfl_xor(s, 8);
    s += __shfl_xor(s, 16);
    s += __shfl_xor(s, 32);
    if (l == 0) stats[col] = s;
}

// ---------------------------------------------------------------- BN-fold + FC
__global__ __launch_bounds__(256) void k_out(
        const unsigned short* __restrict__ h, const float* __restrict__ stats,
        const float* __restrict__ gamma, const float* __restrict__ beta,
        const float* __restrict__ Wfc, const float* __restrict__ bfc,
        float* __restrict__ out, int N) {
    __shared__ float sWm[64 * 16];
    __shared__ float sShift[64];
    __shared__ float sBase[16];
    const int tid = threadIdx.x;
    const float invN = 1.0f / (float)N;
    if (tid < 64) {
        float mu = stats[tid] * invN;
        float var = stats[64 + tid] * invN - mu * mu;
        float sc = gamma[tid] / sqrtf(var + 1e-5f);
        sShift[tid] = beta[tid] - mu * sc;
#pragma unroll
        for (int c = 0; c < 16; ++c) sWm[tid * 16 + c] = Wfc[c * 64 + tid] * sc;
    }
    __syncthreads();
    if (tid < 16) {
        float b = bfc[tid];
#pragma unroll
        for (int j = 0; j < 64; ++j) b += sShift[j] * Wfc[tid * 64 + j];
        sBase[tid] = b;
    }
    __syncthreads();
    int g = blockIdx.x * 256 + tid;
    int n = g >> 4;
    int c = g & 15;
    if (n >= N) return;
    const ushort4* h4 = (const ushort4*)(h + (size_t)n * 64);
    float acc = sBase[c];
#pragma unroll
    for (int jq = 0; jq < 16; ++jq) {
        ushort4 v = h4[jq];
        acc += bf2f(v.x) * sWm[(jq * 4 + 0) * 16 + c];
        acc += bf2f(v.y) * sWm[(jq * 4 + 1) * 16 + c];
        acc += bf2f(v.z) * sWm[(jq * 4 + 2) * 16 + c];
        acc += bf2f(v.w) * sWm[(jq * 4 + 3) * 16 + c];
    }
    out[(size_t)n * 16 + c] = acc;
}

extern "C" void kernel_launch(void* const* d_in, const int* in_sizes, int n_in,
                              void* d_out, int out_size, void* d_ws, size_t ws_size,
                              hipStream_t stream) {
    const int* eidx = (const int*)d_in[0];
    const float* x = (const float*)d_in[1];
    const float* Wl = (const float*)d_in[2];
    const float* bl = (const float*)d_in[3];
    const float* Wr = (const float*)d_in[4];
    const float* gamma = (const float*)d_in[5];
    const float* beta = (const float*)d_in[6];
    const float* Wfc = (const float*)d_in[7];
    const float* bfc = (const float*)d_in[8];
    float* out = (float*)d_out;

    const int E = in_sizes[0] / 2;
    const int N = in_sizes[1] / 64;
    const int fblocks = (N + 63) / 64;
    const int sblocks = (N + 1023) / 1024;

    int* deg = (int*)d_ws;                                     // N (zeroed)
    int* rowptr = deg + N;                                     // N+1
    int* colv = rowptr + (N + 1);                              // E
    int* rank = colv + E;                                      // E
    unsigned short* mh = (unsigned short*)(rank + E);          // N*64 bf16
    float* pstats = (float*)(mh + (size_t)N * 64);             // fblocks*128
    float* stats = pstats + (size_t)fblocks * 128;             // 128
    int* bsum = (int*)(stats + 128);                           // 256
    unsigned short* xbf = (unsigned short*)(bsum + 256);       // N*64 bf16 (optional)

    size_t need_bf = (size_t)((char*)(xbf + (size_t)N * 64) - (char*)d_ws);
    const bool use_bf16_x = (ws_size >= need_bf);

    hipMemsetAsync(d_ws, 0, (size_t)N * 4, stream);

    int eblocks = (E + 255) / 256;
    k_histrank<<<eblocks, 256, 0, stream>>>(eidx, deg, rank, E);
    k_scan1<<<sblocks, 256, 0, stream>>>(deg, rowptr, bsum, N);
    k_scan2<<<1, 256, 0, stream>>>(bsum, sblocks);
    k_scan3<<<sblocks, 256, 0, stream>>>(rowptr, bsum, N, E);
    k_fill<<<eblocks, 256, 0, stream>>>(eidx, rowptr, rank, colv, E);

    int gblocks = (int)(((size_t)N * 16 + 255) / 256);
    if (use_bf16_x) {
        k_xcast<<<gblocks, 256, 0, stream>>>((const float4*)x, (ushort4*)xbf, N * 16);
        k_gather_bf<<<gblocks, 256, 0, stream>>>((const ushort4*)xbf, rowptr, colv,
                                                 (ushort4*)mh, N);
    } else {
        k_gather_f32<<<gblocks, 256, 0, stream>>>((const float4*)x, rowptr, colv,
                                                  (ushort4*)mh, N);
    }

    k_fused<<<fblocks, 256, 0, stream>>>(x, Wl, bl, Wr, mh, pstats, N);

    k_stats<<<128, 64, 0, stream>>>(pstats, stats, fblocks);

    int oblocks = (int)(((size_t)N * 16 + 255) / 256);
    k_out<<<oblocks, 256, 0, stream>>>(mh, stats, gamma, beta, Wfc, bfc, out, N);
}